// Round 23
// baseline (351.138 us; speedup 1.0000x reference)
//
#include <hip/hip_runtime.h>
#include <hip/hip_bf16.h>
#include <math.h>

#define NB 32
#define CK 512
#define C1 1024
#define CA 80
#define CQ 80
#define CQ2 160
#define TEN 400
#define TDE 2000
#define KDIM 1536
#define TPAD 448
#define TQP 2048

static constexpr float TEMP = 0.0005f;

typedef __attribute__((ext_vector_type(8))) short short8;
typedef __attribute__((ext_vector_type(4))) float f32x4;

__device__ inline short f2bf(float v) {
  __hip_bfloat16 h = __float2bfloat16(v);
  return *(short*)&h;
}
__device__ inline float bf2f(short s) {
  __hip_bfloat16 h = *(__hip_bfloat16*)&s;
  return __bfloat162float(h);
}

__device__ inline void gload_lds16(const void* g, void* l) {
  __builtin_amdgcn_global_load_lds(
      (const __attribute__((address_space(1))) unsigned int*)g,
      (__attribute__((address_space(3))) unsigned int*)l, 16, 0, 0);
}

// ---------------------------------------------------------------------------
// Fused weight conversion (verbatim R20/R22)
// ---------------------------------------------------------------------------
__global__ __launch_bounds__(256) void cvt_weights_kernel(
    const float* __restrict__ kw1, const float* __restrict__ kw2,
    const float* __restrict__ qw1, const float* __restrict__ qw2,
    const float* __restrict__ qw3, short* __restrict__ w1bf,
    short* __restrict__ w2bf, short* __restrict__ w1q,
    short* __restrict__ w2q, short* __restrict__ w3q) {
  int i = blockIdx.x * 256 + threadIdx.x;
  if (i < 1572864) {
    w1bf[i] = f2bf(kw1[i]);
    return;
  }
  i -= 1572864;
  if (i < 131072) {
    int r = i >> 10, c = i & 1023;
    w2bf[i] = f2bf(r < CA ? kw2[r * 1024 + c] : 0.f);
    return;
  }
  i -= 131072;
  if (i < 49152) {
    int r = i >> 8, c = i & 255;
    w1q[i] = f2bf((r < CQ2 && c < 240) ? qw1[r * 240 + c] : 0.f);
    return;
  }
  i -= 49152;
  if (i < 20480) {
    int r = i / 160, c = i - r * 160;
    w2q[i] = f2bf(r < CA ? qw2[r * 160 + c] : 0.f);
    return;
  }
  i -= 20480;
  if (i < 12288) {
    int r = i / 96, c = i - r * 96;
    w3q[i] = f2bf((r < CA && c < CQ) ? qw3[r * 80 + c] : 0.f);
  }
}

// ---------------------------------------------------------------------------
// Keys im2col v2: LDS-staged, short8-vectorized. Same output values as v1.
// Block = (64-wide t tile, b); 8 ci-chunks of 64. Rows t>=400 untouched.
// ---------------------------------------------------------------------------
__global__ __launch_bounds__(256) void im2col_kernel(
    const float* __restrict__ keys, short* __restrict__ BmatT) {
  __shared__ float sq[64][66];
  const int t0 = blockIdx.x * 64;      // 7 tiles: 0..384
  const int b = blockIdx.y;
  const int tid = threadIdx.x;
  for (int ci0 = 0; ci0 < CK; ci0 += 64) {
    for (int idx = tid; idx < 64 * 66; idx += 256) {
      int c = idx / 66, j = idx % 66;
      int t = t0 - 1 + j;
      sq[c][j] = (t >= 0 && t < TEN) ? keys[((size_t)b * CK + ci0 + c) * TEN + t] : 0.f;
    }
    __syncthreads();
    for (int idx = tid; idx < 64 * 24; idx += 256) {
      int j = idx / 24, seg = idx % 24;
      if (t0 + j < TEN) {
        short8 v;
        #pragma unroll
        for (int u = 0; u < 8; ++u) {
          int kk = seg * 8 + u;          // 0..191 within chunk
          int ci = kk / 3, dk = kk - ci * 3;
          v[u] = f2bf(sq[ci][j + dk]);
        }
        *(short8*)(BmatT + ((size_t)b * TPAD + t0 + j) * KDIM + ci0 * 3 + seg * 8) = v;
      }
    }
    __syncthreads();
  }
}

// ---------------------------------------------------------------------------
// Queries im2col v2: LDS-staged, short8-vectorized. Same output values as v1.
// Block = (64-wide t tile, b). Rows t>=2000 and k>=240 zeroed.
// ---------------------------------------------------------------------------
__global__ __launch_bounds__(256) void im2col_q_kernel(
    const float* __restrict__ queries, short* __restrict__ Bq) {
  __shared__ float sq[80][66];
  const int t0 = blockIdx.x * 64;      // 32 tiles: 0..1984 (TQP=2048)
  const int b = blockIdx.y;
  const int tid = threadIdx.x;
  for (int idx = tid; idx < 80 * 66; idx += 256) {
    int c = idx / 66, j = idx % 66;
    int t = t0 - 1 + j;
    sq[c][j] = (t >= 0 && t < TDE) ? queries[((size_t)b * CQ + c) * TDE + t] : 0.f;
  }
  __syncthreads();
  for (int idx = tid; idx < 64 * 32; idx += 256) {
    int j = idx >> 5, seg = idx & 31;
    const bool live = (t0 + j) < TDE;
    short8 v;
    #pragma unroll
    for (int u = 0; u < 8; ++u) {
      int k = seg * 8 + u;
      float f = 0.f;
      if (live && k < 240) {
        int ci = k / 3, dk = k - ci * 3;
        f = sq[ci][j + dk];
      }
      v[u] = f2bf(f);
    }
    *(short8*)(Bq + ((size_t)b * TQP + t0 + j) * 256 + seg * 8) = v;
  }
}

// ---------------------------------------------------------------------------
// Key conv1 via MFMA v4 (verbatim R20/R22): 128x128 tile, gload_lds(16B),
// L2-locality remap. -> k1t[b][t][co] bf16
// ---------------------------------------------------------------------------
__global__ __launch_bounds__(256) void kconv1_mfma_kernel(
    const short* __restrict__ w1bf, const short* __restrict__ BmatT,
    const float* __restrict__ b1, short* __restrict__ k1t) {
  __shared__ short A_lds[4096];
  __shared__ short B_lds[4096];
  const int flat = blockIdx.x;
  const int cox = flat >> 7;
  const int rem = flat & 127;
  const int b   = rem >> 2;
  const int ty  = rem & 3;
  const int co0 = cox * 128;
  const int t0  = ty * 128;
  const int tid = threadIdx.x;
  const int l = tid & 63, w = tid >> 6;

  auto invswz = [](int Y) {
    int X = Y;
    X ^= ((Y >> 8) & 1) << 6;
    X ^= ((Y >> 7) & 1) << 5;
    X ^= (((Y >> 6) ^ (Y >> 8)) & 1) << 4;
    return X;
  };

  const short* gsrc[4];
  short* ldst[4];
  #pragma unroll
  for (int j = 0; j < 4; ++j) {
    int c = w * 4 + j;
    int Y = (c & 7) * 1024 + l * 16;
    int X = invswz(Y);
    int row = X >> 6, slot = (X >> 4) & 3;
    if (c < 8) {
      gsrc[j] = w1bf + (size_t)(co0 + row) * KDIM + slot * 8;
      ldst[j] = &A_lds[(c & 7) * 512];
    } else {
      int gr = t0 + row;
      if (gr > TPAD - 1) gr = TPAD - 1;
      gsrc[j] = BmatT + ((size_t)b * TPAD + gr) * KDIM + slot * 8;
      ldst[j] = &B_lds[(c & 7) * 512];
    }
  }

  const int kslot = l >> 4;
  int abyte[2];
  #pragma unroll
  for (int i = 0; i < 2; ++i) {
    int arow = w * 32 + i * 16 + (l & 15);
    abyte[i] = (arow * 64 + kslot * 16) ^ ((arow & 7) << 4);
  }
  int bbyte[8];
  #pragma unroll
  for (int g = 0; g < 8; ++g) {
    int brow = g * 16 + (l & 15);
    bbyte[g] = (brow * 64 + kslot * 16) ^ ((brow & 7) << 4);
  }

  f32x4 acc[2][8];
  #pragma unroll
  for (int i = 0; i < 2; ++i)
    #pragma unroll
    for (int g = 0; g < 8; ++g) acc[i][g] = (f32x4){0.f, 0.f, 0.f, 0.f};

  for (int kt = 0; kt < KDIM / 32; ++kt) {
    __syncthreads();
    #pragma unroll
    for (int j = 0; j < 4; ++j) gload_lds16(gsrc[j] + kt * 32, ldst[j]);
    __syncthreads();
    short8 a0 = *(const short8*)((const char*)A_lds + abyte[0]);
    short8 a1 = *(const short8*)((const char*)A_lds + abyte[1]);
    #pragma unroll
    for (int g = 0; g < 8; ++g) {
      short8 bb = *(const short8*)((const char*)B_lds + bbyte[g]);
      acc[0][g] = __builtin_amdgcn_mfma_f32_16x16x32_bf16(a0, bb, acc[0][g], 0, 0, 0);
      acc[1][g] = __builtin_amdgcn_mfma_f32_16x16x32_bf16(a1, bb, acc[1][g], 0, 0, 0);
    }
  }

  #pragma unroll
  for (int g = 0; g < 8; ++g) {
    int t = t0 + g * 16 + (l & 15);
    if (t < TEN) {
      #pragma unroll
      for (int i = 0; i < 2; ++i) {
        #pragma unroll
        for (int r = 0; r < 4; ++r) {
          int co = co0 + w * 32 + i * 16 + kslot * 4 + r;
          float v = acc[i][g][r] + b1[co];
          k1t[((size_t)b * TPAD + t) * C1 + co] = f2bf(v > 0.f ? v : 0.f);
        }
      }
    }
  }
}

// ---------------------------------------------------------------------------
// Generic small GEMM + prefetch (verbatim R17-R22 template).
// MODE 1: bf16 [b][t][co] (cols in [M,outCols) zeroed); MODE 2: f32 [b][co][t]
// ---------------------------------------------------------------------------
template <int MODE, bool RELU>
__global__ __launch_bounds__(256) void qgemm_kernel(
    const short* __restrict__ A, const short* __restrict__ B,
    const float* __restrict__ bias, void* __restrict__ outv,
    int M, int Kpad, int kiters, int Nvalid, int outCols,
    size_t bBatchStride, size_t outBatchStride, int outLD) {
  __shared__ short A_lds[2048];
  __shared__ short B_lds[2048];
  const int co0 = blockIdx.x * 64;
  const int t0  = blockIdx.y * 64;
  const int b   = blockIdx.z;
  const int tid = threadIdx.x;
  const int l = tid & 63, w = tid >> 6;
  const int srow = tid >> 2, sslot = tid & 3;

  const short* gA = A + (size_t)(co0 + srow) * Kpad + sslot * 8;
  const short* gB = B + (size_t)b * bBatchStride + (size_t)(t0 + srow) * Kpad + sslot * 8;
  const int wbyte = (srow * 64 + sslot * 16) ^ ((srow & 7) << 4);

  const int kslot = l >> 4;
  const int arow = w * 16 + (l & 15);
  const int abyte = (arow * 64 + kslot * 16) ^ ((arow & 7) << 4);
  int bbyte[4];
  #pragma unroll
  for (int g = 0; g < 4; ++g) {
    int brow = g * 16 + (l & 15);
    bbyte[g] = (brow * 64 + kslot * 16) ^ ((brow & 7) << 4);
  }

  f32x4 acc[4];
  #pragma unroll
  for (int g = 0; g < 4; ++g) acc[g] = (f32x4){0.f, 0.f, 0.f, 0.f};

  uint4 av = *(const uint4*)gA;
  uint4 bv = *(const uint4*)gB;
  for (int kt = 0; kt < kiters; ++kt) {
    __syncthreads();
    *(uint4*)((char*)A_lds + wbyte) = av;
    *(uint4*)((char*)B_lds + wbyte) = bv;
    __syncthreads();
    uint4 an = av, bn = bv;
    if (kt + 1 < kiters) {
      an = *(const uint4*)(gA + (kt + 1) * 32);
      bn = *(const uint4*)(gB + (kt + 1) * 32);
    }
    short8 a = *(const short8*)((const char*)A_lds + abyte);
    #pragma unroll
    for (int g = 0; g < 4; ++g) {
      short8 bb = *(const short8*)((const char*)B_lds + bbyte[g]);
      acc[g] = __builtin_amdgcn_mfma_f32_16x16x32_bf16(a, bb, acc[g], 0, 0, 0);
    }
    av = an; bv = bn;
  }

  #pragma unroll
  for (int g = 0; g < 4; ++g) {
    int t = t0 + g * 16 + (l & 15);
    if (t >= Nvalid) continue;
    #pragma unroll
    for (int r = 0; r < 4; ++r) {
      int co = co0 + w * 16 + kslot * 4 + r;
      if (MODE == 1) {
        if (co < outCols) {
          float v = 0.f;
          if (co < M) {
            v = acc[g][r] + bias[co];
            if (RELU) v = v > 0.f ? v : 0.f;
          }
          ((short*)outv)[(size_t)b * outBatchStride + (size_t)t * outLD + co] = f2bf(v);
        }
      } else {
        if (co < M) {
          float v = acc[g][r] + bias[co];
          if (RELU) v = v > 0.f ? v : 0.f;
          ((float*)outv)[(size_t)b * outBatchStride + (size_t)co * outLD + t] = v;
        }
      }
    }
  }
}

// ---------------------------------------------------------------------------
// Norms (verbatim R20/R22)
// ---------------------------------------------------------------------------
__global__ __launch_bounds__(256) void norms_kernel(
    const short* __restrict__ qA, const short* __restrict__ kB,
    float* __restrict__ q2n, float* __restrict__ k2n) {
  const int tid = threadIdx.x;
  const int R = blockIdx.x * 64 + (tid >> 2);
  const int g = tid & 3;
  const short* src;
  float* dst;
  if (R < NB * TQP) {
    src = qA + (size_t)R * 96 + g * 24;
    dst = q2n + R;
  } else {
    int R2 = R - NB * TQP;
    if (R2 >= NB * TPAD) return;
    src = kB + (size_t)R2 * 96 + g * 24;
    dst = k2n + R2;
  }
  float s = 0.f;
  #pragma unroll
  for (int c = 0; c < 3; ++c) {
    short8 v = *(const short8*)(src + c * 8);
    #pragma unroll
    for (int j = 0; j < 8; ++j) {
      float f = bf2f(v[j]);
      s += f * f;
    }
  }
  s += __shfl_xor(s, 1, 64);
  s += __shfl_xor(s, 2, 64);
  if (g == 0) *dst = s;
}

// ---------------------------------------------------------------------------
// FUSED attention (verbatim R17-R22)
// ---------------------------------------------------------------------------
__global__ __launch_bounds__(256) void attn_fused_kernel(
    const short* __restrict__ qA, const short* __restrict__ kB,
    const float* __restrict__ q2, const float* __restrict__ k2,
    const int* __restrict__ mask, float* __restrict__ out_attn,
    float* __restrict__ out_logp) {
  __shared__ short A_lds[3][2048];
  __shared__ short B_lds[3][2560];
  __shared__ float k2LDS[400];
  __shared__ int mLDS[400];
  const int t0 = blockIdx.x * 64;
  const int b  = blockIdx.y;
  const int tid = threadIdx.x;
  const int l = tid & 63, w = tid >> 6;

  {
    const int arow_s = tid >> 2, aslot = tid & 3;
    const short* gA = qA + ((size_t)b * TQP + t0 + arow_s) * 96 + aslot * 8;
    #pragma unroll
    for (int p = 0; p < 3; ++p) {
      uint4 v = *(const uint4*)(gA + p * 32);
      *(uint4*)((char*)&A_lds[p][0] +
                ((arow_s * 64 + aslot * 16) ^ ((arow_s & 7) << 4))) = v;
    }
  }
  for (int idx = tid; idx < 400; idx += 256) {
    k2LDS[idx] = k2[(size_t)b * TPAD + idx];
    mLDS[idx] = mask[(size_t)b * TEN + idx];
  }

  const int kslot = l >> 4;
  const int arow = w * 16 + (l & 15);
  const int abyte = (arow * 64 + kslot * 16) ^ ((arow & 7) << 4);

  f32x4 acc[25];
  #pragma unroll
  for (int i = 0; i < 25; ++i) acc[i] = (f32x4){0.f, 0.f, 0.f, 0.f};

  __syncthreads();
  #pragma unroll
  for (int st = 0; st < 5; ++st) {
    for (int idx = tid; idx < 960; idx += 256) {
      int row = idx / 12, c = idx - row * 12;
      int panel = c >> 2, ps = c & 3;
      uint4 v = *(const uint4*)(kB + ((size_t)b * TPAD + st * 80 + row) * 96 + c * 8);
      *(uint4*)((char*)&B_lds[panel][0] +
                ((row * 64 + ps * 16) ^ ((row & 7) << 4))) = v;
    }
    __syncthreads();
    #pragma unroll
    for (int kt = 0; kt < 3; ++kt) {
      short8 a = *(const short8*)((const char*)&A_lds[kt][0] + abyte);
      #pragma unroll
      for (int f = 0; f < 5; ++f) {
        int brow = f * 16 + (l & 15);
        short8 bb = *(const short8*)((const char*)&B_lds[kt][0] +
                                     ((brow * 64 + kslot * 16) ^ ((brow & 7) << 4)));
        acc[st * 5 + f] =
            __builtin_amdgcn_mfma_f32_16x16x32_bf16(a, bb, acc[st * 5 + f], 0, 0, 0);
      }
    }
    __syncthreads();
  }

  int trow[4]; float q2v[4];
  #pragma unroll
  for (int r = 0; r < 4; ++r) {
    trow[r] = t0 + w * 16 + kslot * 4 + r;
    q2v[r] = q2[(size_t)b * TQP + trow[r]];
  }
  #pragma unroll
  for (int sf = 0; sf < 25; ++sf) {
    int s = sf * 16 + (l & 15);
    float k2v = k2LDS[s];
    bool mk = mLDS[s] != 0;
    #pragma unroll
    for (int r = 0; r < 4; ++r) {
      float lp = mk ? (-TEMP) * (q2v[r] + k2v - 2.f * acc[sf][r]) : -INFINITY;
      acc[sf][r] = lp;
    }
  }
  #pragma unroll
  for (int r = 0; r < 4; ++r) {
    if (trow[r] < TDE) {
      float* dst = out_logp + ((size_t)(b * TDE + trow[r])) * TEN + (l & 15);
      #pragma unroll
      for (int sf = 0; sf < 25; ++sf) dst[sf * 16] = acc[sf][r];
    }
  }
  float m[4];
  #pragma unroll
  for (int r = 0; r < 4; ++r) m[r] = -INFINITY;
  #pragma unroll
  for (int sf = 0; sf < 25; ++sf)
    #pragma unroll
    for (int r = 0; r < 4; ++r) m[r] = fmaxf(m[r], acc[sf][r]);
  #pragma unroll
  for (int o = 1; o < 16; o <<= 1)
    #pragma unroll
    for (int r = 0; r < 4; ++r) m[r] = fmaxf(m[r], __shfl_xor(m[r], o, 64));
  float sum[4] = {0.f, 0.f, 0.f, 0.f};
  #pragma unroll
  for (int sf = 0; sf < 25; ++sf)
    #pragma unroll
    for (int r = 0; r < 4; ++r) {
      float v = acc[sf][r];
      float e = (v != -INFINITY) ? __expf(v - m[r]) : 0.f;
      acc[sf][r] = e;
      sum[r] += e;
    }
  #pragma unroll
  for (int o = 1; o < 16; o <<= 1)
    #pragma unroll
    for (int r = 0; r < 4; ++r) sum[r] += __shfl_xor(sum[r], o, 64);
  float inv[4];
  #pragma unroll
  for (int r = 0; r < 4; ++r) inv[r] = 1.0f / sum[r];
  #pragma unroll
  for (int r = 0; r < 4; ++r) {
    if (trow[r] < TDE) {
      float* dst = out_attn + ((size_t)(b * TDE + trow[r])) * TEN + (l & 15);
      #pragma unroll
      for (int sf = 0; sf < 25; ++sf) dst[sf * 16] = acc[sf][r] * inv[r];
    }
  }
}

extern "C" void kernel_launch(void* const* d_in, const int* in_sizes, int n_in,
                              void* d_out, int out_size, void* d_ws, size_t ws_size,
                              hipStream_t stream) {
  const float* queries = (const float*)d_in[0];
  const float* keys    = (const float*)d_in[1];
  const int*   mask    = (const int*)d_in[2];
  const float* kw1 = (const float*)d_in[3];
  const float* kb1 = (const float*)d_in[4];
  const float* kw2 = (const float*)d_in[5];
  const float* kb2 = (const float*)d_in[6];
  const float* qw1 = (const float*)d_in[7];
  const float* qb1 = (const float*)d_in[8];
  const float* qw2 = (const float*)d_in[9];
  const float* qb2 = (const float*)d_in[10];
  const float* qw3 = (const float*)d_in[11];
  const float* qb3 = (const float*)d_in[12];
  float* out = (float*)d_out;

  char* ws = (char*)d_ws;
  short* BmatT = (short*)ws;
  short* w1bf  = (short*)(ws + 44040192);
  short* k1t   = (short*)(ws + 47185920);
  short* w2bf  = (short*)(ws + 76546048);
  short* w1q   = (short*)(ws + 76808192);
  short* w2q   = (short*)(ws + 76906496);
  short* w3q   = (short*)(ws + 76947456);
  short* Bq    = (short*)ws;
  short* q1bf  = (short*)(ws + 33554432);
  short* q2bf  = (short*)(ws + 54525952);
  short* qA    = (short*)(ws + 20480000);
  float* q2n   = (float*)(ws + 33062912);
  float* k2n   = (float*)(ws + 49938432);
  short* kB    = (short*)(ws + 81920000);

  const long long HALF = 25600000LL;
  float* out_attn = out;
  float* out_logp = out + HALF;

  // --- weights (one fused launch) ---
  cvt_weights_kernel<<<dim3(6976), dim3(256), 0, stream>>>(
      kw1, kw2, qw1, qw2, qw3, w1bf, w2bf, w1q, w2q, w3q);

  // --- key path ---
  im2col_kernel<<<dim3(7, NB), dim3(256), 0, stream>>>(keys, BmatT);
  kconv1_mfma_kernel<<<dim3(1024), dim3(256), 0, stream>>>(w1bf, BmatT, kb1, k1t);
  qgemm_kernel<1, false><<<dim3(2, 7, NB), dim3(256), 0, stream>>>(
      w2bf, k1t, kb2, kB, CA, C1, 32, TEN, 96,
      (size_t)TPAD * C1, (size_t)TPAD * 96, 96);

  // --- query path (MFMA chain -> qA bf16 directly) ---
  im2col_q_kernel<<<dim3(TQP / 64, NB), dim3(256), 0, stream>>>(queries, Bq);
  qgemm_kernel<1, true><<<dim3(3, TQP / 64, NB), dim3(256), 0, stream>>>(
      w1q, Bq, qb1, q1bf, CQ2, 256, 8, TQP, 160,
      (size_t)TQP * 256, (size_t)TQP * 160, 160);
  qgemm_kernel<1, true><<<dim3(2, TQP / 64, NB), dim3(256), 0, stream>>>(
      w2q, q1bf, qb2, q2bf, CA, 160, 5, TQP, 96,
      (size_t)TQP * 160, (size_t)TQP * 96, 96);
  qgemm_kernel<1, false><<<dim3(2, TQP / 64, NB), dim3(256), 0, stream>>>(
      w3q, q2bf, qb3, qA, CA, 96, 3, TQP, 96,
      (size_t)TQP * 96, (size_t)TQP * 96, 96);

  // --- norms + fused attention ---
  norms_kernel<<<dim3((NB * TQP + NB * TPAD) / 64), dim3(256), 0, stream>>>(
      qA, kB, q2n, k2n);
  attn_fused_kernel<<<dim3(TQP / 64, NB), dim3(256), 0, stream>>>(
      qA, kB, q2n, k2n, mask, out_attn, out_logp);
}

// Round 25
// 340.128 us; speedup vs baseline: 1.0324x; 1.0324x over previous
//
#include <hip/hip_runtime.h>
#include <hip/hip_bf16.h>
#include <math.h>

#define NB 32
#define CK 512
#define C1 1024
#define CA 80
#define CQ 80
#define CQ2 160
#define TEN 400
#define TDE 2000
#define KDIM 1536
#define TPAD 448
#define TQP 2048

static constexpr float TEMP = 0.0005f;

typedef __attribute__((ext_vector_type(8))) short short8;
typedef __attribute__((ext_vector_type(4))) float f32x4;

__device__ inline short f2bf(float v) {
  __hip_bfloat16 h = __float2bfloat16(v);
  return *(short*)&h;
}
__device__ inline float bf2f(short s) {
  __hip_bfloat16 h = *(__hip_bfloat16*)&s;
  return __bfloat162float(h);
}

__device__ inline void gload_lds16(const void* g, void* l) {
  __builtin_amdgcn_global_load_lds(
      (const __attribute__((address_space(1))) unsigned int*)g,
      (__attribute__((address_space(3))) unsigned int*)l, 16, 0, 0);
}

// ===========================================================================
// Device bodies (verbatim logic from proven R22/R23 kernels)
// ===========================================================================

__device__ void cvt_weights_body(
    int i0, const float* __restrict__ kw1, const float* __restrict__ kw2,
    const float* __restrict__ qw1, const float* __restrict__ qw2,
    const float* __restrict__ qw3, short* __restrict__ w1bf,
    short* __restrict__ w2bf, short* __restrict__ w1q,
    short* __restrict__ w2q, short* __restrict__ w3q) {
  int i = i0 * 256 + threadIdx.x;
  if (i < 1572864) {
    w1bf[i] = f2bf(kw1[i]);
    return;
  }
  i -= 1572864;
  if (i < 131072) {
    int r = i >> 10, c = i & 1023;
    w2bf[i] = f2bf(r < CA ? kw2[r * 1024 + c] : 0.f);
    return;
  }
  i -= 131072;
  if (i < 49152) {
    int r = i >> 8, c = i & 255;
    w1q[i] = f2bf((r < CQ2 && c < 240) ? qw1[r * 240 + c] : 0.f);
    return;
  }
  i -= 49152;
  if (i < 20480) {
    int r = i / 160, c = i - r * 160;
    w2q[i] = f2bf(r < CA ? qw2[r * 160 + c] : 0.f);
    return;
  }
  i -= 20480;
  if (i < 12288) {
    int r = i / 96, c = i - r * 96;
    w3q[i] = f2bf((r < CA && c < CQ) ? qw3[r * 80 + c] : 0.f);
  }
}

__device__ void im2col_k_body(int idx, const float* __restrict__ keys,
                              short* __restrict__ BmatT, float* sq /*[64*66]*/) {
  const int t0 = (idx % 7) * 64;
  const int b = idx / 7;
  const int tid = threadIdx.x;
  for (int ci0 = 0; ci0 < CK; ci0 += 64) {
    for (int k = tid; k < 64 * 66; k += 256) {
      int c = k / 66, j = k % 66;
      int t = t0 - 1 + j;
      sq[c * 66 + j] =
          (t >= 0 && t < TEN) ? keys[((size_t)b * CK + ci0 + c) * TEN + t] : 0.f;
    }
    __syncthreads();
    for (int k = tid; k < 64 * 24; k += 256) {
      int j = k / 24, seg = k % 24;
      if (t0 + j < TEN) {
        short8 v;
        #pragma unroll
        for (int u = 0; u < 8; ++u) {
          int kk = seg * 8 + u;
          int ci = kk / 3, dk = kk - ci * 3;
          v[u] = f2bf(sq[ci * 66 + j + dk]);
        }
        *(short8*)(BmatT + ((size_t)b * TPAD + t0 + j) * KDIM + ci0 * 3 + seg * 8) = v;
      }
    }
    __syncthreads();
  }
}

__device__ void im2col_q_body(int idx, const float* __restrict__ queries,
                              short* __restrict__ Bq, float* sq /*[80*66]*/) {
  const int t0 = (idx & 31) * 64;
  const int b = idx >> 5;
  const int tid = threadIdx.x;
  for (int k = tid; k < 80 * 66; k += 256) {
    int c = k / 66, j = k % 66;
    int t = t0 - 1 + j;
    sq[c * 66 + j] =
        (t >= 0 && t < TDE) ? queries[((size_t)b * CQ + c) * TDE + t] : 0.f;
  }
  __syncthreads();
  for (int k = tid; k < 64 * 32; k += 256) {
    int j = k >> 5, seg = k & 31;
    const bool live = (t0 + j) < TDE;
    short8 v;
    #pragma unroll
    for (int u = 0; u < 8; ++u) {
      int kk = seg * 8 + u;
      float f = 0.f;
      if (live && kk < 240) {
        int ci = kk / 3, dk = kk - ci * 3;
        f = sq[ci * 66 + j + dk];
      }
      v[u] = f2bf(f);
    }
    *(short8*)(Bq + ((size_t)b * TQP + t0 + j) * 256 + seg * 8) = v;
  }
}

template <int MODE, bool RELU>
__device__ void qgemm_body(int bx, int by, int bz,
                           const short* __restrict__ A, const short* __restrict__ B,
                           const float* __restrict__ bias, void* __restrict__ outv,
                           int M, int Kpad, int kiters, int Nvalid, int outCols,
                           size_t bBatchStride, size_t outBatchStride, int outLD,
                           short* A_lds /*[2048]*/, short* B_lds /*[2048]*/) {
  const int co0 = bx * 64;
  const int t0  = by * 64;
  const int b   = bz;
  const int tid = threadIdx.x;
  const int l = tid & 63, w = tid >> 6;
  const int srow = tid >> 2, sslot = tid & 3;

  const short* gA = A + (size_t)(co0 + srow) * Kpad + sslot * 8;
  const short* gB = B + (size_t)b * bBatchStride + (size_t)(t0 + srow) * Kpad + sslot * 8;
  const int wbyte = (srow * 64 + sslot * 16) ^ ((srow & 7) << 4);

  const int kslot = l >> 4;
  const int arow = w * 16 + (l & 15);
  const int abyte = (arow * 64 + kslot * 16) ^ ((arow & 7) << 4);
  int bbyte[4];
  #pragma unroll
  for (int g = 0; g < 4; ++g) {
    int brow = g * 16 + (l & 15);
    bbyte[g] = (brow * 64 + kslot * 16) ^ ((brow & 7) << 4);
  }

  f32x4 acc[4];
  #pragma unroll
  for (int g = 0; g < 4; ++g) acc[g] = (f32x4){0.f, 0.f, 0.f, 0.f};

  uint4 av = *(const uint4*)gA;
  uint4 bv = *(const uint4*)gB;
  for (int kt = 0; kt < kiters; ++kt) {
    __syncthreads();
    *(uint4*)((char*)A_lds + wbyte) = av;
    *(uint4*)((char*)B_lds + wbyte) = bv;
    __syncthreads();
    uint4 an = av, bn = bv;
    if (kt + 1 < kiters) {
      an = *(const uint4*)(gA + (kt + 1) * 32);
      bn = *(const uint4*)(gB + (kt + 1) * 32);
    }
    short8 a = *(const short8*)((const char*)A_lds + abyte);
    #pragma unroll
    for (int g = 0; g < 4; ++g) {
      short8 bb = *(const short8*)((const char*)B_lds + bbyte[g]);
      acc[g] = __builtin_amdgcn_mfma_f32_16x16x32_bf16(a, bb, acc[g], 0, 0, 0);
    }
    av = an; bv = bn;
  }

  #pragma unroll
  for (int g = 0; g < 4; ++g) {
    int t = t0 + g * 16 + (l & 15);
    if (t >= Nvalid) continue;
    #pragma unroll
    for (int r = 0; r < 4; ++r) {
      int co = co0 + w * 16 + kslot * 4 + r;
      if (MODE == 1) {
        if (co < outCols) {
          float v = 0.f;
          if (co < M) {
            v = acc[g][r] + bias[co];
            if (RELU) v = v > 0.f ? v : 0.f;
          }
          ((short*)outv)[(size_t)b * outBatchStride + (size_t)t * outLD + co] = f2bf(v);
        }
      } else {
        if (co < M) {
          float v = acc[g][r] + bias[co];
          if (RELU) v = v > 0.f ? v : 0.f;
          ((float*)outv)[(size_t)b * outBatchStride + (size_t)co * outLD + t] = v;
        }
      }
    }
  }
}

// ===========================================================================
// Stage kernels (overlay-aware packing)
// ===========================================================================

// stageA: cvt_weights [0,6976) | im2col_k [6976,7200)
// (disjoint outputs: weights @44.04M+, BmatT @[0,44.04M))
__global__ __launch_bounds__(256) void stageA_kernel(
    const float* __restrict__ kw1, const float* __restrict__ kw2,
    const float* __restrict__ qw1, const float* __restrict__ qw2,
    const float* __restrict__ qw3, short* __restrict__ w1bf,
    short* __restrict__ w2bf, short* __restrict__ w1q,
    short* __restrict__ w2q, short* __restrict__ w3q,
    const float* __restrict__ keys, short* __restrict__ BmatT) {
  __shared__ float sq[64 * 66];
  int flat = blockIdx.x;
  if (flat < 6976) {
    cvt_weights_body(flat, kw1, kw2, qw1, qw2, qw3, w1bf, w2bf, w1q, w2q, w3q);
  } else {
    im2col_k_body(flat - 6976, keys, BmatT, sq);
  }
}

// ---------------------------------------------------------------------------
// Key conv1 via MFMA v4 (verbatim R22/R23, standalone)
// ---------------------------------------------------------------------------
__global__ __launch_bounds__(256) void kconv1_mfma_kernel(
    const short* __restrict__ w1bf, const short* __restrict__ BmatT,
    const float* __restrict__ b1, short* __restrict__ k1t) {
  __shared__ short A_lds[4096];
  __shared__ short B_lds[4096];
  const int flat = blockIdx.x;
  const int cox = flat >> 7;
  const int rem = flat & 127;
  const int b   = rem >> 2;
  const int ty  = rem & 3;
  const int co0 = cox * 128;
  const int t0  = ty * 128;
  const int tid = threadIdx.x;
  const int l = tid & 63, w = tid >> 6;

  auto invswz = [](int Y) {
    int X = Y;
    X ^= ((Y >> 8) & 1) << 6;
    X ^= ((Y >> 7) & 1) << 5;
    X ^= (((Y >> 6) ^ (Y >> 8)) & 1) << 4;
    return X;
  };

  const short* gsrc[4];
  short* ldst[4];
  #pragma unroll
  for (int j = 0; j < 4; ++j) {
    int c = w * 4 + j;
    int Y = (c & 7) * 1024 + l * 16;
    int X = invswz(Y);
    int row = X >> 6, slot = (X >> 4) & 3;
    if (c < 8) {
      gsrc[j] = w1bf + (size_t)(co0 + row) * KDIM + slot * 8;
      ldst[j] = &A_lds[(c & 7) * 512];
    } else {
      int gr = t0 + row;
      if (gr > TPAD - 1) gr = TPAD - 1;
      gsrc[j] = BmatT + ((size_t)b * TPAD + gr) * KDIM + slot * 8;
      ldst[j] = &B_lds[(c & 7) * 512];
    }
  }

  const int kslot = l >> 4;
  int abyte[2];
  #pragma unroll
  for (int i = 0; i < 2; ++i) {
    int arow = w * 32 + i * 16 + (l & 15);
    abyte[i] = (arow * 64 + kslot * 16) ^ ((arow & 7) << 4);
  }
  int bbyte[8];
  #pragma unroll
  for (int g = 0; g < 8; ++g) {
    int brow = g * 16 + (l & 15);
    bbyte[g] = (brow * 64 + kslot * 16) ^ ((brow & 7) << 4);
  }

  f32x4 acc[2][8];
  #pragma unroll
  for (int i = 0; i < 2; ++i)
    #pragma unroll
    for (int g = 0; g < 8; ++g) acc[i][g] = (f32x4){0.f, 0.f, 0.f, 0.f};

  for (int kt = 0; kt < KDIM / 32; ++kt) {
    __syncthreads();
    #pragma unroll
    for (int j = 0; j < 4; ++j) gload_lds16(gsrc[j] + kt * 32, ldst[j]);
    __syncthreads();
    short8 a0 = *(const short8*)((const char*)A_lds + abyte[0]);
    short8 a1 = *(const short8*)((const char*)A_lds + abyte[1]);
    #pragma unroll
    for (int g = 0; g < 8; ++g) {
      short8 bb = *(const short8*)((const char*)B_lds + bbyte[g]);
      acc[0][g] = __builtin_amdgcn_mfma_f32_16x16x32_bf16(a0, bb, acc[0][g], 0, 0, 0);
      acc[1][g] = __builtin_amdgcn_mfma_f32_16x16x32_bf16(a1, bb, acc[1][g], 0, 0, 0);
    }
  }

  #pragma unroll
  for (int g = 0; g < 8; ++g) {
    int t = t0 + g * 16 + (l & 15);
    if (t < TEN) {
      #pragma unroll
      for (int i = 0; i < 2; ++i) {
        #pragma unroll
        for (int r = 0; r < 4; ++r) {
          int co = co0 + w * 32 + i * 16 + kslot * 4 + r;
          float v = acc[i][g][r] + b1[co];
          k1t[((size_t)b * TPAD + t) * C1 + co] = f2bf(v > 0.f ? v : 0.f);
        }
      }
    }
  }
}

// stageC: im2col_q [0,1024) | kconv2-GEMM [1024,1472)
// (Bq @[0,33.55M) safe: BmatT dead after kconv1; kconv2 reads k1t @47.19M+)
__global__ __launch_bounds__(256) void stageC_kernel(
    const float* __restrict__ queries, short* __restrict__ Bq,
    const short* __restrict__ w2bf, const short* __restrict__ k1t,
    const float* __restrict__ kb2, short* __restrict__ kB) {
  __shared__ __align__(16) char pool[21120];   // max(80*66*4, 2*4096)
  int flat = blockIdx.x;
  if (flat < 1024) {
    im2col_q_body(flat, queries, Bq, (float*)pool);
  } else {
    int j = flat - 1024;
    int bx = j & 1, rest = j >> 1;
    int by = rest % 7, bz = rest / 7;
    qgemm_body<1, false>(bx, by, bz, w2bf, k1t, kb2, kB, CA, C1, 32, TEN, 96,
                         (size_t)TPAD * C1, (size_t)TPAD * 96, 96,
                         (short*)pool, (short*)(pool + 4096));
  }
}

// ---------------------------------------------------------------------------
// Standalone qgemm (verbatim wrapper over qgemm_body)
// ---------------------------------------------------------------------------
template <int MODE, bool RELU>
__global__ __launch_bounds__(256) void qgemm_kernel(
    const short* __restrict__ A, const short* __restrict__ B,
    const float* __restrict__ bias, void* __restrict__ outv,
    int M, int Kpad, int kiters, int Nvalid, int outCols,
    size_t bBatchStride, size_t outBatchStride, int outLD) {
  __shared__ short A_lds[2048];
  __shared__ short B_lds[2048];
  qgemm_body<MODE, RELU>(blockIdx.x, blockIdx.y, blockIdx.z, A, B, bias, outv,
                         M, Kpad, kiters, Nvalid, outCols, bBatchStride,
                         outBatchStride, outLD, A_lds, B_lds);
}

// ---------------------------------------------------------------------------
// Norms (verbatim R22/R23)
// ---------------------------------------------------------------------------
__global__ __launch_bounds__(256) void norms_kernel(
    const short* __restrict__ qA, const short* __restrict__ kB,
    float* __restrict__ q2n, float* __restrict__ k2n) {
  const int tid = threadIdx.x;
  const int R = blockIdx.x * 64 + (tid >> 2);
  const int g = tid & 3;
  const short* src;
  float* dst;
  if (R < NB * TQP) {
    src = qA + (size_t)R * 96 + g * 24;
    dst = q2n + R;
  } else {
    int R2 = R - NB * TQP;
    if (R2 >= NB * TPAD) return;
    src = kB + (size_t)R2 * 96 + g * 24;
    dst = k2n + R2;
  }
  float s = 0.f;
  #pragma unroll
  for (int c = 0; c < 3; ++c) {
    short8 v = *(const short8*)(src + c * 8);
    #pragma unroll
    for (int j = 0; j < 8; ++j) {
      float f = bf2f(v[j]);
      s += f * f;
    }
  }
  s += __shfl_xor(s, 1, 64);
  s += __shfl_xor(s, 2, 64);
  if (g == 0) *dst = s;
}

// ---------------------------------------------------------------------------
// FUSED attention (verbatim R17-R23)
// ---------------------------------------------------------------------------
__global__ __launch_bounds__(256) void attn_fused_kernel(
    const short* __restrict__ qA, const short* __restrict__ kB,
    const float* __restrict__ q2, const float* __restrict__ k2,
    const int* __restrict__ mask, float* __restrict__ out_attn,
    float* __restrict__ out_logp) {
  __shared__ short A_lds[3][2048];
  __shared__ short B_lds[3][2560];
  __shared__ float k2LDS[400];
  __shared__ int mLDS[400];
  const int t0 = blockIdx.x * 64;
  const int b  = blockIdx.y;
  const int tid = threadIdx.x;
  const int l = tid & 63, w = tid >> 6;

  {
    const int arow_s = tid >> 2, aslot = tid & 3;
    const short* gA = qA + ((size_t)b * TQP + t0 + arow_s) * 96 + aslot * 8;
    #pragma unroll
    for (int p = 0; p < 3; ++p) {
      uint4 v = *(const uint4*)(gA + p * 32);
      *(uint4*)((char*)&A_lds[p][0] +
                ((arow_s * 64 + aslot * 16) ^ ((arow_s & 7) << 4))) = v;
    }
  }
  for (int idx = tid; idx < 400; idx += 256) {
    k2LDS[idx] = k2[(size_t)b * TPAD + idx];
    mLDS[idx] = mask[(size_t)b * TEN + idx];
  }

  const int kslot = l >> 4;
  const int arow = w * 16 + (l & 15);
  const int abyte = (arow * 64 + kslot * 16) ^ ((arow & 7) << 4);

  f32x4 acc[25];
  #pragma unroll
  for (int i = 0; i < 25; ++i) acc[i] = (f32x4){0.f, 0.f, 0.f, 0.f};

  __syncthreads();
  #pragma unroll
  for (int st = 0; st < 5; ++st) {
    for (int idx = tid; idx < 960; idx += 256) {
      int row = idx / 12, c = idx - row * 12;
      int panel = c >> 2, ps = c & 3;
      uint4 v = *(const uint4*)(kB + ((size_t)b * TPAD + st * 80 + row) * 96 + c * 8);
      *(uint4*)((char*)&B_lds[panel][0] +
                ((row * 64 + ps * 16) ^ ((row & 7) << 4))) = v;
    }
    __syncthreads();
    #pragma unroll
    for (int kt = 0; kt < 3; ++kt) {
      short8 a = *(const short8*)((const char*)&A_lds[kt][0] + abyte);
      #pragma unroll
      for (int f = 0; f < 5; ++f) {
        int brow = f * 16 + (l & 15);
        short8 bb = *(const short8*)((const char*)&B_lds[kt][0] +
                                     ((brow * 64 + kslot * 16) ^ ((brow & 7) << 4)));
        acc[st * 5 + f] =
            __builtin_amdgcn_mfma_f32_16x16x32_bf16(a, bb, acc[st * 5 + f], 0, 0, 0);
      }
    }
    __syncthreads();
  }

  int trow[4]; float q2v[4];
  #pragma unroll
  for (int r = 0; r < 4; ++r) {
    trow[r] = t0 + w * 16 + kslot * 4 + r;
    q2v[r] = q2[(size_t)b * TQP + trow[r]];
  }
  #pragma unroll
  for (int sf = 0; sf < 25; ++sf) {
    int s = sf * 16 + (l & 15);
    float k2v = k2LDS[s];
    bool mk = mLDS[s] != 0;
    #pragma unroll
    for (int r = 0; r < 4; ++r) {
      float lp = mk ? (-TEMP) * (q2v[r] + k2v - 2.f * acc[sf][r]) : -INFINITY;
      acc[sf][r] = lp;
    }
  }
  #pragma unroll
  for (int r = 0; r < 4; ++r) {
    if (trow[r] < TDE) {
      float* dst = out_logp + ((size_t)(b * TDE + trow[r])) * TEN + (l & 15);
      #pragma unroll
      for (int sf = 0; sf < 25; ++sf) dst[sf * 16] = acc[sf][r];
    }
  }
  float m[4];
  #pragma unroll
  for (int r = 0; r < 4; ++r) m[r] = -INFINITY;
  #pragma unroll
  for (int sf = 0; sf < 25; ++sf)
    #pragma unroll
    for (int r = 0; r < 4; ++r) m[r] = fmaxf(m[r], acc[sf][r]);
  #pragma unroll
  for (int o = 1; o < 16; o <<= 1)
    #pragma unroll
    for (int r = 0; r < 4; ++r) m[r] = fmaxf(m[r], __shfl_xor(m[r], o, 64));
  float sum[4] = {0.f, 0.f, 0.f, 0.f};
  #pragma unroll
  for (int sf = 0; sf < 25; ++sf)
    #pragma unroll
    for (int r = 0; r < 4; ++r) {
      float v = acc[sf][r];
      float e = (v != -INFINITY) ? __expf(v - m[r]) : 0.f;
      acc[sf][r] = e;
      sum[r] += e;
    }
  #pragma unroll
  for (int o = 1; o < 16; o <<= 1)
    #pragma unroll
    for (int r = 0; r < 4; ++r) sum[r] += __shfl_xor(sum[r], o, 64);
  float inv[4];
  #pragma unroll
  for (int r = 0; r < 4; ++r) inv[r] = 1.0f / sum[r];
  #pragma unroll
  for (int r = 0; r < 4; ++r) {
    if (trow[r] < TDE) {
      float* dst = out_attn + ((size_t)(b * TDE + trow[r])) * TEN + (l & 15);
      #pragma unroll
      for (int sf = 0; sf < 25; ++sf) dst[sf * 16] = acc[sf][r] * inv[r];
    }
  }
}

extern "C" void kernel_launch(void* const* d_in, const int* in_sizes, int n_in,
                              void* d_out, int out_size, void* d_ws, size_t ws_size,
                              hipStream_t stream) {
  const float* queries = (const float*)d_in[0];
  const float* keys    = (const float*)d_in[1];
  const int*   mask    = (const int*)d_in[2];
  const float* kw1 = (const float*)d_in[3];
  const float* kb1 = (const float*)d_in[4];
  const float* kw2 = (const float*)d_in[5];
  const float* kb2 = (const float*)d_in[6];
  const float* qw1 = (const float*)d_in[7];
  const float* qb1 = (const float*)d_in[8];
  const float* qw2 = (const float*)d_in[9];
  const float* qb2 = (const float*)d_in[10];
  const float* qw3 = (const float*)d_in[11];
  const float* qb3 = (const float*)d_in[12];
  float* out = (float*)d_out;

  char* ws = (char*)d_ws;
  // Overlay schedule (stream-ordered; aliasing edges enforce launch order):
  //  stageA: BmatT [0,44.04M) + weights [44.04M,76.97M slice)
  //  kconv1: reads BmatT -> k1t [47.19M,76.55M)
  //  stageC: Bq [0,33.55M) (BmatT dead) + kB [81.92M,84.67M) (reads k1t)
  //  qgemm1: q1bf [33.55M,54.53M) (k1t dead)
  //  qgemm2: q2bf [54.53M,67.11M); qgemm3: qA [20.48M,33.06M) (Bq dead)
  short* BmatT = (short*)ws;
  short* w1bf  = (short*)(ws + 44040192);
  short* k1t   = (short*)(ws + 47185920);
  short* w2bf  = (short*)(ws + 76546048);
  short* w1q   = (short*)(ws + 76808192);
  short* w2q   = (short*)(ws + 76906496);
  short* w3q   = (short*)(ws + 76947456);
  short* Bq    = (short*)ws;
  short* q1bf  = (short*)(ws + 33554432);
  short* q2bf  = (short*)(ws + 54525952);
  short* qA    = (short*)(ws + 20480000);
  float* q2n   = (float*)(ws + 33062912);
  float* k2n   = (float*)(ws + 49938432);
  short* kB    = (short*)(ws + 81920000);

  const long long HALF = 25600000LL;
  float* out_attn = out;
  float* out_logp = out + HALF;

  // stageA: weights cvt + im2col_k (disjoint outputs)
  stageA_kernel<<<dim3(7200), dim3(256), 0, stream>>>(
      kw1, kw2, qw1, qw2, qw3, w1bf, w2bf, w1q, w2q, w3q, keys, BmatT);

  // kconv1 (consumes BmatT)
  kconv1_mfma_kernel<<<dim3(1024), dim3(256), 0, stream>>>(w1bf, BmatT, kb1, k1t);

  // stageC: im2col_q + kconv2-GEMM (BmatT dead; no aliasing)
  stageC_kernel<<<dim3(1472), dim3(256), 0, stream>>>(
      queries, Bq, w2bf, k1t, kb2, kB);

  // query GEMM chain
  qgemm_kernel<1, true><<<dim3(3, TQP / 64, NB), dim3(256), 0, stream>>>(
      w1q, Bq, qb1, q1bf, CQ2, 256, 8, TQP, 160,
      (size_t)TQP * 256, (size_t)TQP * 160, 160);
  qgemm_kernel<1, true><<<dim3(2, TQP / 64, NB), dim3(256), 0, stream>>>(
      w2q, q1bf, qb2, q2bf, CA, 160, 5, TQP, 96,
      (size_t)TQP * 160, (size_t)TQP * 96, 96);
  qgemm_kernel<1, false><<<dim3(2, TQP / 64, NB), dim3(256), 0, stream>>>(
      w3q, q2bf, qb3, qA, CA, 96, 3, TQP, 96,
      (size_t)TQP * 96, (size_t)TQP * 96, 96);

  // norms + fused attention
  norms_kernel<<<dim3((NB * TQP + NB * TPAD) / 64), dim3(256), 0, stream>>>(
      qA, kB, q2n, k2n);
  attn_fused_kernel<<<dim3(TQP / 64, NB), dim3(256), 0, stream>>>(
      qA, kB, q2n, k2n, mask, out_attn, out_logp);
}

// Round 26
// 332.300 us; speedup vs baseline: 1.0567x; 1.0236x over previous
//
#include <hip/hip_runtime.h>
#include <hip/hip_bf16.h>
#include <math.h>

#define NB 32
#define CK 512
#define C1 1024
#define CA 80
#define CQ 80
#define CQ2 160
#define TEN 400
#define TDE 2000
#define KDIM 1536
#define TPAD 448
#define TQP 2048

static constexpr float TEMP = 0.0005f;

typedef __attribute__((ext_vector_type(8))) short short8;
typedef __attribute__((ext_vector_type(4))) float f32x4;

__device__ inline short f2bf(float v) {
  __hip_bfloat16 h = __float2bfloat16(v);
  return *(short*)&h;
}
__device__ inline float bf2f(short s) {
  __hip_bfloat16 h = *(__hip_bfloat16*)&s;
  return __bfloat162float(h);
}

__device__ inline void gload_lds16(const void* g, void* l) {
  __builtin_amdgcn_global_load_lds(
      (const __attribute__((address_space(1))) unsigned int*)g,
      (__attribute__((address_space(3))) unsigned int*)l, 16, 0, 0);
}

// ===========================================================================
// Device bodies (verbatim logic from proven R22/R25 kernels)
// ===========================================================================

__device__ void cvt_weights_body(
    int i0, const float* __restrict__ kw1, const float* __restrict__ kw2,
    const float* __restrict__ qw1, const float* __restrict__ qw2,
    const float* __restrict__ qw3, short* __restrict__ w1bf,
    short* __restrict__ w2bf, short* __restrict__ w1q,
    short* __restrict__ w2q, short* __restrict__ w3q) {
  int i = i0 * 256 + threadIdx.x;
  if (i < 1572864) {
    w1bf[i] = f2bf(kw1[i]);
    return;
  }
  i -= 1572864;
  if (i < 131072) {
    int r = i >> 10, c = i & 1023;
    w2bf[i] = f2bf(r < CA ? kw2[r * 1024 + c] : 0.f);
    return;
  }
  i -= 131072;
  if (i < 49152) {
    int r = i >> 8, c = i & 255;
    w1q[i] = f2bf((r < CQ2 && c < 240) ? qw1[r * 240 + c] : 0.f);
    return;
  }
  i -= 49152;
  if (i < 20480) {
    int r = i / 160, c = i - r * 160;
    w2q[i] = f2bf(r < CA ? qw2[r * 160 + c] : 0.f);
    return;
  }
  i -= 20480;
  if (i < 12288) {
    int r = i / 96, c = i - r * 96;
    w3q[i] = f2bf((r < CA && c < CQ) ? qw3[r * 80 + c] : 0.f);
  }
}

__device__ void im2col_k_body(int idx, const float* __restrict__ keys,
                              short* __restrict__ BmatT, float* sq /*[64*66]*/) {
  const int t0 = (idx % 7) * 64;
  const int b = idx / 7;
  const int tid = threadIdx.x;
  for (int ci0 = 0; ci0 < CK; ci0 += 64) {
    for (int k = tid; k < 64 * 66; k += 256) {
      int c = k / 66, j = k % 66;
      int t = t0 - 1 + j;
      sq[c * 66 + j] =
          (t >= 0 && t < TEN) ? keys[((size_t)b * CK + ci0 + c) * TEN + t] : 0.f;
    }
    __syncthreads();
    for (int k = tid; k < 64 * 24; k += 256) {
      int j = k / 24, seg = k % 24;
      if (t0 + j < TEN) {
        short8 v;
        #pragma unroll
        for (int u = 0; u < 8; ++u) {
          int kk = seg * 8 + u;
          int ci = kk / 3, dk = kk - ci * 3;
          v[u] = f2bf(sq[ci * 66 + j + dk]);
        }
        *(short8*)(BmatT + ((size_t)b * TPAD + t0 + j) * KDIM + ci0 * 3 + seg * 8) = v;
      }
    }
    __syncthreads();
  }
}

__device__ void im2col_q_body(int idx, const float* __restrict__ queries,
                              short* __restrict__ Bq, float* sq /*[80*66]*/) {
  const int t0 = (idx & 31) * 64;
  const int b = idx >> 5;
  const int tid = threadIdx.x;
  for (int k = tid; k < 80 * 66; k += 256) {
    int c = k / 66, j = k % 66;
    int t = t0 - 1 + j;
    sq[c * 66 + j] =
        (t >= 0 && t < TDE) ? queries[((size_t)b * CQ + c) * TDE + t] : 0.f;
  }
  __syncthreads();
  for (int k = tid; k < 64 * 32; k += 256) {
    int j = k >> 5, seg = k & 31;
    const bool live = (t0 + j) < TDE;
    short8 v;
    #pragma unroll
    for (int u = 0; u < 8; ++u) {
      int kk = seg * 8 + u;
      float f = 0.f;
      if (live && kk < 240) {
        int ci = kk / 3, dk = kk - ci * 3;
        f = sq[ci * 66 + j + dk];
      }
      v[u] = f2bf(f);
    }
    *(short8*)(Bq + ((size_t)b * TQP + t0 + j) * 256 + seg * 8) = v;
  }
}

template <int MODE, bool RELU>
__device__ void qgemm_body(int bx, int by, int bz,
                           const short* __restrict__ A, const short* __restrict__ B,
                           const float* __restrict__ bias, void* __restrict__ outv,
                           int M, int Kpad, int kiters, int Nvalid, int outCols,
                           size_t bBatchStride, size_t outBatchStride, int outLD,
                           short* A_lds /*[2048]*/, short* B_lds /*[2048]*/) {
  const int co0 = bx * 64;
  const int t0  = by * 64;
  const int b   = bz;
  const int tid = threadIdx.x;
  const int l = tid & 63, w = tid >> 6;
  const int srow = tid >> 2, sslot = tid & 3;

  const short* gA = A + (size_t)(co0 + srow) * Kpad + sslot * 8;
  const short* gB = B + (size_t)b * bBatchStride + (size_t)(t0 + srow) * Kpad + sslot * 8;
  const int wbyte = (srow * 64 + sslot * 16) ^ ((srow & 7) << 4);

  const int kslot = l >> 4;
  const int arow = w * 16 + (l & 15);
  const int abyte = (arow * 64 + kslot * 16) ^ ((arow & 7) << 4);
  int bbyte[4];
  #pragma unroll
  for (int g = 0; g < 4; ++g) {
    int brow = g * 16 + (l & 15);
    bbyte[g] = (brow * 64 + kslot * 16) ^ ((brow & 7) << 4);
  }

  f32x4 acc[4];
  #pragma unroll
  for (int g = 0; g < 4; ++g) acc[g] = (f32x4){0.f, 0.f, 0.f, 0.f};

  uint4 av = *(const uint4*)gA;
  uint4 bv = *(const uint4*)gB;
  for (int kt = 0; kt < kiters; ++kt) {
    __syncthreads();
    *(uint4*)((char*)A_lds + wbyte) = av;
    *(uint4*)((char*)B_lds + wbyte) = bv;
    __syncthreads();
    uint4 an = av, bn = bv;
    if (kt + 1 < kiters) {
      an = *(const uint4*)(gA + (kt + 1) * 32);
      bn = *(const uint4*)(gB + (kt + 1) * 32);
    }
    short8 a = *(const short8*)((const char*)A_lds + abyte);
    #pragma unroll
    for (int g = 0; g < 4; ++g) {
      short8 bb = *(const short8*)((const char*)B_lds + bbyte[g]);
      acc[g] = __builtin_amdgcn_mfma_f32_16x16x32_bf16(a, bb, acc[g], 0, 0, 0);
    }
    av = an; bv = bn;
  }

  #pragma unroll
  for (int g = 0; g < 4; ++g) {
    int t = t0 + g * 16 + (l & 15);
    if (t >= Nvalid) continue;
    #pragma unroll
    for (int r = 0; r < 4; ++r) {
      int co = co0 + w * 16 + kslot * 4 + r;
      if (MODE == 1) {
        if (co < outCols) {
          float v = 0.f;
          if (co < M) {
            v = acc[g][r] + bias[co];
            if (RELU) v = v > 0.f ? v : 0.f;
          }
          ((short*)outv)[(size_t)b * outBatchStride + (size_t)t * outLD + co] = f2bf(v);
        }
      } else {
        if (co < M) {
          float v = acc[g][r] + bias[co];
          if (RELU) v = v > 0.f ? v : 0.f;
          ((float*)outv)[(size_t)b * outBatchStride + (size_t)co * outLD + t] = v;
        }
      }
    }
  }
}

// ===========================================================================
// Stage kernels (overlay-aware packing, verbatim R25)
// ===========================================================================

// stageA: cvt_weights [0,6976) | im2col_k [6976,7200)
__global__ __launch_bounds__(256) void stageA_kernel(
    const float* __restrict__ kw1, const float* __restrict__ kw2,
    const float* __restrict__ qw1, const float* __restrict__ qw2,
    const float* __restrict__ qw3, short* __restrict__ w1bf,
    short* __restrict__ w2bf, short* __restrict__ w1q,
    short* __restrict__ w2q, short* __restrict__ w3q,
    const float* __restrict__ keys, short* __restrict__ BmatT) {
  __shared__ float sq[64 * 66];
  int flat = blockIdx.x;
  if (flat < 6976) {
    cvt_weights_body(flat, kw1, kw2, qw1, qw2, qw3, w1bf, w2bf, w1q, w2q, w3q);
  } else {
    im2col_k_body(flat - 6976, keys, BmatT, sq);
  }
}

// ---------------------------------------------------------------------------
// Key conv1 via MFMA v6: 128x128 tile, BK=64, gload_lds(16B) staging.
// Swizzle Y = X ^ (((X>>7)&7)<<4) is SELF-INVERSE at BK=64 (mask bits 4-6
// disjoint from row bits 7+). 24 K-iterations, 32 MFMA/wave per barrier pair.
// MFMA K-order identical to BK=32 version -> bit-identical output.
// ---------------------------------------------------------------------------
__global__ __launch_bounds__(256) void kconv1_mfma_kernel(
    const short* __restrict__ w1bf, const short* __restrict__ BmatT,
    const float* __restrict__ b1, short* __restrict__ k1t) {
  __shared__ short A_lds[8192];   // 128 rows x 64 k (16 KB)
  __shared__ short B_lds[8192];
  const int flat = blockIdx.x;
  const int cox = flat >> 7;
  const int rem = flat & 127;
  const int b   = rem >> 2;
  const int ty  = rem & 3;
  const int co0 = cox * 128;
  const int t0  = ty * 128;
  const int tid = threadIdx.x;
  const int l = tid & 63, w = tid >> 6;

  // 32 staging calls of 1024B: c in [0,16) = A, [16,32) = B. Wave w: c = w*8+j.
  const short* gsrc[8];
  short* ldst[8];
  #pragma unroll
  for (int j = 0; j < 8; ++j) {
    int c = w * 8 + j;
    int Y = (c & 15) * 1024 + l * 16;
    int X = Y ^ (((Y >> 7) & 7) << 4);     // self-inverse swizzle
    int row = X >> 7, slot = (X >> 4) & 7;
    if (c < 16) {
      gsrc[j] = w1bf + (size_t)(co0 + row) * KDIM + slot * 8;
      ldst[j] = &A_lds[(c & 15) * 512];
    } else {
      int gr = t0 + row;
      if (gr > TPAD - 1) gr = TPAD - 1;    // clamp: dropped by t<TEN guard
      gsrc[j] = BmatT + ((size_t)b * TPAD + gr) * KDIM + slot * 8;
      ldst[j] = &B_lds[(c & 15) * 512];
    }
  }

  const int kslot = l >> 4;
  const int li15 = l & 15;
  // read byte offsets per (frag, kk): full linear-then-XOR (no carry hazard)
  int abyte[2][2], bbyte[8][2];
  #pragma unroll
  for (int i = 0; i < 2; ++i) {
    int arow = w * 32 + i * 16 + li15;
    #pragma unroll
    for (int kk = 0; kk < 2; ++kk)
      abyte[i][kk] = (arow * 128 + kk * 64 + kslot * 16) ^ ((arow & 7) << 4);
  }
  #pragma unroll
  for (int g = 0; g < 8; ++g) {
    int brow = g * 16 + li15;
    #pragma unroll
    for (int kk = 0; kk < 2; ++kk)
      bbyte[g][kk] = (brow * 128 + kk * 64 + kslot * 16) ^ ((brow & 7) << 4);
  }

  f32x4 acc[2][8];
  #pragma unroll
  for (int i = 0; i < 2; ++i)
    #pragma unroll
    for (int g = 0; g < 8; ++g) acc[i][g] = (f32x4){0.f, 0.f, 0.f, 0.f};

  for (int kt = 0; kt < KDIM / 64; ++kt) {   // 24 iterations
    __syncthreads();
    #pragma unroll
    for (int j = 0; j < 8; ++j) gload_lds16(gsrc[j] + kt * 64, ldst[j]);
    __syncthreads();
    #pragma unroll
    for (int kk = 0; kk < 2; ++kk) {
      short8 a0 = *(const short8*)((const char*)A_lds + abyte[0][kk]);
      short8 a1 = *(const short8*)((const char*)A_lds + abyte[1][kk]);
      #pragma unroll
      for (int g = 0; g < 8; ++g) {
        short8 bb = *(const short8*)((const char*)B_lds + bbyte[g][kk]);
        acc[0][g] = __builtin_amdgcn_mfma_f32_16x16x32_bf16(a0, bb, acc[0][g], 0, 0, 0);
        acc[1][g] = __builtin_amdgcn_mfma_f32_16x16x32_bf16(a1, bb, acc[1][g], 0, 0, 0);
      }
    }
  }

  #pragma unroll
  for (int g = 0; g < 8; ++g) {
    int t = t0 + g * 16 + li15;
    if (t < TEN) {
      #pragma unroll
      for (int i = 0; i < 2; ++i) {
        #pragma unroll
        for (int r = 0; r < 4; ++r) {
          int co = co0 + w * 32 + i * 16 + kslot * 4 + r;
          float v = acc[i][g][r] + b1[co];
          k1t[((size_t)b * TPAD + t) * C1 + co] = f2bf(v > 0.f ? v : 0.f);
        }
      }
    }
  }
}

// stageC: im2col_q [0,1024) | kconv2-GEMM [1024,1472)  (verbatim R25)
__global__ __launch_bounds__(256) void stageC_kernel(
    const float* __restrict__ queries, short* __restrict__ Bq,
    const short* __restrict__ w2bf, const short* __restrict__ k1t,
    const float* __restrict__ kb2, short* __restrict__ kB) {
  __shared__ __align__(16) char pool[21120];
  int flat = blockIdx.x;
  if (flat < 1024) {
    im2col_q_body(flat, queries, Bq, (float*)pool);
  } else {
    int j = flat - 1024;
    int bx = j & 1, rest = j >> 1;
    int by = rest % 7, bz = rest / 7;
    qgemm_body<1, false>(bx, by, bz, w2bf, k1t, kb2, kB, CA, C1, 32, TEN, 96,
                         (size_t)TPAD * C1, (size_t)TPAD * 96, 96,
                         (short*)pool, (short*)(pool + 4096));
  }
}

// ---------------------------------------------------------------------------
// Standalone qgemm (verbatim R25)
// ---------------------------------------------------------------------------
template <int MODE, bool RELU>
__global__ __launch_bounds__(256) void qgemm_kernel(
    const short* __restrict__ A, const short* __restrict__ B,
    const float* __restrict__ bias, void* __restrict__ outv,
    int M, int Kpad, int kiters, int Nvalid, int outCols,
    size_t bBatchStride, size_t outBatchStride, int outLD) {
  __shared__ short A_lds[2048];
  __shared__ short B_lds[2048];
  qgemm_body<MODE, RELU>(blockIdx.x, blockIdx.y, blockIdx.z, A, B, bias, outv,
                         M, Kpad, kiters, Nvalid, outCols, bBatchStride,
                         outBatchStride, outLD, A_lds, B_lds);
}

// ---------------------------------------------------------------------------
// Norms (verbatim R25)
// ---------------------------------------------------------------------------
__global__ __launch_bounds__(256) void norms_kernel(
    const short* __restrict__ qA, const short* __restrict__ kB,
    float* __restrict__ q2n, float* __restrict__ k2n) {
  const int tid = threadIdx.x;
  const int R = blockIdx.x * 64 + (tid >> 2);
  const int g = tid & 3;
  const short* src;
  float* dst;
  if (R < NB * TQP) {
    src = qA + (size_t)R * 96 + g * 24;
    dst = q2n + R;
  } else {
    int R2 = R - NB * TQP;
    if (R2 >= NB * TPAD) return;
    src = kB + (size_t)R2 * 96 + g * 24;
    dst = k2n + R2;
  }
  float s = 0.f;
  #pragma unroll
  for (int c = 0; c < 3; ++c) {
    short8 v = *(const short8*)(src + c * 8);
    #pragma unroll
    for (int j = 0; j < 8; ++j) {
      float f = bf2f(v[j]);
      s += f * f;
    }
  }
  s += __shfl_xor(s, 1, 64);
  s += __shfl_xor(s, 2, 64);
  if (g == 0) *dst = s;
}

// ---------------------------------------------------------------------------
// FUSED attention (verbatim R17-R25)
// ---------------------------------------------------------------------------
__global__ __launch_bounds__(256) void attn_fused_kernel(
    const short* __restrict__ qA, const short* __restrict__ kB,
    const float* __restrict__ q2, const float* __restrict__ k2,
    const int* __restrict__ mask, float* __restrict__ out_attn,
    float* __restrict__ out_logp) {
  __shared__ short A_lds[3][2048];
  __shared__ short B_lds[3][2560];
  __shared__ float k2LDS[400];
  __shared__ int mLDS[400];
  const int t0 = blockIdx.x * 64;
  const int b  = blockIdx.y;
  const int tid = threadIdx.x;
  const int l = tid & 63, w = tid >> 6;

  {
    const int arow_s = tid >> 2, aslot = tid & 3;
    const short* gA = qA + ((size_t)b * TQP + t0 + arow_s) * 96 + aslot * 8;
    #pragma unroll
    for (int p = 0; p < 3; ++p) {
      uint4 v = *(const uint4*)(gA + p * 32);
      *(uint4*)((char*)&A_lds[p][0] +
                ((arow_s * 64 + aslot * 16) ^ ((arow_s & 7) << 4))) = v;
    }
  }
  for (int idx = tid; idx < 400; idx += 256) {
    k2LDS[idx] = k2[(size_t)b * TPAD + idx];
    mLDS[idx] = mask[(size_t)b * TEN + idx];
  }

  const int kslot = l >> 4;
  const int arow = w * 16 + (l & 15);
  const int abyte = (arow * 64 + kslot * 16) ^ ((arow & 7) << 4);

  f32x4 acc[25];
  #pragma unroll
  for (int i = 0; i < 25; ++i) acc[i] = (f32x4){0.f, 0.f, 0.f, 0.f};

  __syncthreads();
  #pragma unroll
  for (int st = 0; st < 5; ++st) {
    for (int idx = tid; idx < 960; idx += 256) {
      int row = idx / 12, c = idx - row * 12;
      int panel = c >> 2, ps = c & 3;
      uint4 v = *(const uint4*)(kB + ((size_t)b * TPAD + st * 80 + row) * 96 + c * 8);
      *(uint4*)((char*)&B_lds[panel][0] +
                ((row * 64 + ps * 16) ^ ((row & 7) << 4))) = v;
    }
    __syncthreads();
    #pragma unroll
    for (int kt = 0; kt < 3; ++kt) {
      short8 a = *(const short8*)((const char*)&A_lds[kt][0] + abyte);
      #pragma unroll
      for (int f = 0; f < 5; ++f) {
        int brow = f * 16 + (l & 15);
        short8 bb = *(const short8*)((const char*)&B_lds[kt][0] +
                                     ((brow * 64 + kslot * 16) ^ ((brow & 7) << 4)));
        acc[st * 5 + f] =
            __builtin_amdgcn_mfma_f32_16x16x32_bf16(a, bb, acc[st * 5 + f], 0, 0, 0);
      }
    }
    __syncthreads();
  }

  int trow[4]; float q2v[4];
  #pragma unroll
  for (int r = 0; r < 4; ++r) {
    trow[r] = t0 + w * 16 + kslot * 4 + r;
    q2v[r] = q2[(size_t)b * TQP + trow[r]];
  }
  #pragma unroll
  for (int sf = 0; sf < 25; ++sf) {
    int s = sf * 16 + (l & 15);
    float k2v = k2LDS[s];
    bool mk = mLDS[s] != 0;
    #pragma unroll
    for (int r = 0; r < 4; ++r) {
      float lp = mk ? (-TEMP) * (q2v[r] + k2v - 2.f * acc[sf][r]) : -INFINITY;
      acc[sf][r] = lp;
    }
  }
  #pragma unroll
  for (int r = 0; r < 4; ++r) {
    if (trow[r] < TDE) {
      float* dst = out_logp + ((size_t)(b * TDE + trow[r])) * TEN + (l & 15);
      #pragma unroll
      for (int sf = 0; sf < 25; ++sf) dst[sf * 16] = acc[sf][r];
    }
  }
  float m[4];
  #pragma unroll
  for (int r = 0; r < 4; ++r) m[r] = -INFINITY;
  #pragma unroll
  for (int sf = 0; sf < 25; ++sf)
    #pragma unroll
    for (int r = 0; r < 4; ++r) m[r] = fmaxf(m[r], acc[sf][r]);
  #pragma unroll
  for (int o = 1; o < 16; o <<= 1)
    #pragma unroll
    for (int r = 0; r < 4; ++r) m[r] = fmaxf(m[r], __shfl_xor(m[r], o, 64));
  float sum[4] = {0.f, 0.f, 0.f, 0.f};
  #pragma unroll
  for (int sf = 0; sf < 25; ++sf)
    #pragma unroll
    for (int r = 0; r < 4; ++r) {
      float v = acc[sf][r];
      float e = (v != -INFINITY) ? __expf(v - m[r]) : 0.f;
      acc[sf][r] = e;
      sum[r] += e;
    }
  #pragma unroll
  for (int o = 1; o < 16; o <<= 1)
    #pragma unroll
    for (int r = 0; r < 4; ++r) sum[r] += __shfl_xor(sum[r], o, 64);
  float inv[4];
  #pragma unroll
  for (int r = 0; r < 4; ++r) inv[r] = 1.0f / sum[r];
  #pragma unroll
  for (int r = 0; r < 4; ++r) {
    if (trow[r] < TDE) {
      float* dst = out_attn + ((size_t)(b * TDE + trow[r])) * TEN + (l & 15);
      #pragma unroll
      for (int sf = 0; sf < 25; ++sf) dst[sf * 16] = acc[sf][r] * inv[r];
    }
  }
}

extern "C" void kernel_launch(void* const* d_in, const int* in_sizes, int n_in,
                              void* d_out, int out_size, void* d_ws, size_t ws_size,
                              hipStream_t stream) {
  const float* queries = (const float*)d_in[0];
  const float* keys    = (const float*)d_in[1];
  const int*   mask    = (const int*)d_in[2];
  const float* kw1 = (const float*)d_in[3];
  const float* kb1 = (const float*)d_in[4];
  const float* kw2 = (const float*)d_in[5];
  const float* kb2 = (const float*)d_in[6];
  const float* qw1 = (const float*)d_in[7];
  const float* qb1 = (const float*)d_in[8];
  const float* qw2 = (const float*)d_in[9];
  const float* qb2 = (const float*)d_in[10];
  const float* qw3 = (const float*)d_in[11];
  const float* qb3 = (const float*)d_in[12];
  float* out = (float*)d_out;

  char* ws = (char*)d_ws;
  short* BmatT = (short*)ws;
  short* w1bf  = (short*)(ws + 44040192);
  short* k1t   = (short*)(ws + 47185920);
  short* w2bf  = (short*)(ws + 76546048);
  short* w1q   = (short*)(ws + 76808192);
  short* w2q   = (short*)(ws + 76906496);
  short* w3q   = (short*)(ws + 76947456);
  short* Bq    = (short*)ws;
  short* q1bf  = (short*)(ws + 33554432);
  short* q2bf  = (short*)(ws + 54525952);
  short* qA    = (short*)(ws + 20480000);
  float* q2n   = (float*)(ws + 33062912);
  float* k2n   = (float*)(ws + 49938432);
  short* kB    = (short*)(ws + 81920000);

  const long long HALF = 25600000LL;
  float* out_attn = out;
  float* out_logp = out + HALF;

  // stageA: weights cvt + im2col_k (disjoint outputs)
  stageA_kernel<<<dim3(7200), dim3(256), 0, stream>>>(
      kw1, kw2, qw1, qw2, qw3, w1bf, w2bf, w1q, w2q, w3q, keys, BmatT);

  // kconv1 (consumes BmatT)
  kconv1_mfma_kernel<<<dim3(1024), dim3(256), 0, stream>>>(w1bf, BmatT, kb1, k1t);

  // stageC: im2col_q + kconv2-GEMM
  stageC_kernel<<<dim3(1472), dim3(256), 0, stream>>>(
      queries, Bq, w2bf, k1t, kb2, kB);

  // query GEMM chain
  qgemm_kernel<1, true><<<dim3(3, TQP / 64, NB), dim3(256), 0, stream>>>(
      w1q, Bq, qb1, q1bf, CQ2, 256, 8, TQP, 160,
      (size_t)TQP * 256, (size_t)TQP * 160, 160);
  qgemm_kernel<1, true><<<dim3(2, TQP / 64, NB), dim3(256), 0, stream>>>(
      w2q, q1bf, qb2, q2bf, CA, 160, 5, TQP, 96,
      (size_t)TQP * 160, (size_t)TQP * 96, 96);
  qgemm_kernel<1, false><<<dim3(2, TQP / 64, NB), dim3(256), 0, stream>>>(
      w3q, q2bf, qb3, qA, CA, 96, 3, TQP, 96,
      (size_t)TQP * 96, (size_t)TQP * 96, 96);

  // norms + fused attention
  norms_kernel<<<dim3((NB * TQP + NB * TPAD) / 64), dim3(256), 0, stream>>>(
      qA, kB, q2n, k2n);
  attn_fused_kernel<<<dim3(TQP / 64, NB), dim3(256), 0, stream>>>(
      qA, kB, q2n, k2n, mask, out_attn, out_logp);
}

// Round 27
// 328.104 us; speedup vs baseline: 1.0702x; 1.0128x over previous
//
#include <hip/hip_runtime.h>
#include <hip/hip_bf16.h>
#include <math.h>

#define NB 32
#define CK 512
#define C1 1024
#define CA 80
#define CQ 80
#define CQ2 160
#define TEN 400
#define TDE 2000
#define KDIM 1536
#define TPAD 448
#define TQP 2048

static constexpr float TEMP = 0.0005f;

typedef __attribute__((ext_vector_type(8))) short short8;
typedef __attribute__((ext_vector_type(4))) float f32x4;

__device__ inline short f2bf(float v) {
  __hip_bfloat16 h = __float2bfloat16(v);
  return *(short*)&h;
}
__device__ inline float bf2f(short s) {
  __hip_bfloat16 h = *(__hip_bfloat16*)&s;
  return __bfloat162float(h);
}

__device__ inline void gload_lds16(const void* g, void* l) {
  __builtin_amdgcn_global_load_lds(
      (const __attribute__((address_space(1))) unsigned int*)g,
      (__attribute__((address_space(3))) unsigned int*)l, 16, 0, 0);
}

// ===========================================================================
// Device bodies (verbatim logic from proven R25/R26 kernels)
// ===========================================================================

__device__ void cvt_weights_body(
    int i0, const float* __restrict__ kw1, const float* __restrict__ kw2,
    const float* __restrict__ qw1, const float* __restrict__ qw2,
    const float* __restrict__ qw3, short* __restrict__ w1bf,
    short* __restrict__ w2bf, short* __restrict__ w1q,
    short* __restrict__ w2q, short* __restrict__ w3q) {
  int i = i0 * 256 + threadIdx.x;
  if (i < 1572864) {
    w1bf[i] = f2bf(kw1[i]);
    return;
  }
  i -= 1572864;
  if (i < 131072) {
    int r = i >> 10, c = i & 1023;
    w2bf[i] = f2bf(r < CA ? kw2[r * 1024 + c] : 0.f);
    return;
  }
  i -= 131072;
  if (i < 49152) {
    int r = i >> 8, c = i & 255;
    w1q[i] = f2bf((r < CQ2 && c < 240) ? qw1[r * 240 + c] : 0.f);
    return;
  }
  i -= 49152;
  if (i < 20480) {
    int r = i / 160, c = i - r * 160;
    w2q[i] = f2bf(r < CA ? qw2[r * 160 + c] : 0.f);
    return;
  }
  i -= 20480;
  if (i < 12288) {
    int r = i / 96, c = i - r * 96;
    w3q[i] = f2bf((r < CA && c < CQ) ? qw3[r * 80 + c] : 0.f);
  }
}

__device__ void im2col_k_body(int idx, const float* __restrict__ keys,
                              short* __restrict__ BmatT, float* sq /*[64*66]*/) {
  const int t0 = (idx % 7) * 64;
  const int b = idx / 7;
  const int tid = threadIdx.x;
  for (int ci0 = 0; ci0 < CK; ci0 += 64) {
    for (int k = tid; k < 64 * 66; k += 256) {
      int c = k / 66, j = k % 66;
      int t = t0 - 1 + j;
      sq[c * 66 + j] =
          (t >= 0 && t < TEN) ? keys[((size_t)b * CK + ci0 + c) * TEN + t] : 0.f;
    }
    __syncthreads();
    for (int k = tid; k < 64 * 24; k += 256) {
      int j = k / 24, seg = k % 24;
      if (t0 + j < TEN) {
        short8 v;
        #pragma unroll
        for (int u = 0; u < 8; ++u) {
          int kk = seg * 8 + u;
          int ci = kk / 3, dk = kk - ci * 3;
          v[u] = f2bf(sq[ci * 66 + j + dk]);
        }
        *(short8*)(BmatT + ((size_t)b * TPAD + t0 + j) * KDIM + ci0 * 3 + seg * 8) = v;
      }
    }
    __syncthreads();
  }
}

__device__ void im2col_q_body(int idx, const float* __restrict__ queries,
                              short* __restrict__ Bq, float* sq /*[80*66]*/) {
  const int t0 = (idx & 31) * 64;
  const int b = idx >> 5;
  const int tid = threadIdx.x;
  for (int k = tid; k < 80 * 66; k += 256) {
    int c = k / 66, j = k % 66;
    int t = t0 - 1 + j;
    sq[c * 66 + j] =
        (t >= 0 && t < TDE) ? queries[((size_t)b * CQ + c) * TDE + t] : 0.f;
  }
  __syncthreads();
  for (int k = tid; k < 64 * 32; k += 256) {
    int j = k >> 5, seg = k & 31;
    const bool live = (t0 + j) < TDE;
    short8 v;
    #pragma unroll
    for (int u = 0; u < 8; ++u) {
      int kk = seg * 8 + u;
      float f = 0.f;
      if (live && kk < 240) {
        int ci = kk / 3, dk = kk - ci * 3;
        f = sq[ci * 66 + j + dk];
      }
      v[u] = f2bf(f);
    }
    *(short8*)(Bq + ((size_t)b * TQP + t0 + j) * 256 + seg * 8) = v;
  }
}

template <int MODE, bool RELU>
__device__ void qgemm_body(int bx, int by, int bz,
                           const short* __restrict__ A, const short* __restrict__ B,
                           const float* __restrict__ bias, void* __restrict__ outv,
                           int M, int Kpad, int kiters, int Nvalid, int outCols,
                           size_t bBatchStride, size_t outBatchStride, int outLD,
                           short* A_lds /*[2048]*/, short* B_lds /*[2048]*/) {
  const int co0 = bx * 64;
  const int t0  = by * 64;
  const int b   = bz;
  const int tid = threadIdx.x;
  const int l = tid & 63, w = tid >> 6;
  const int srow = tid >> 2, sslot = tid & 3;

  const short* gA = A + (size_t)(co0 + srow) * Kpad + sslot * 8;
  const short* gB = B + (size_t)b * bBatchStride + (size_t)(t0 + srow) * Kpad + sslot * 8;
  const int wbyte = (srow * 64 + sslot * 16) ^ ((srow & 7) << 4);

  const int kslot = l >> 4;
  const int arow = w * 16 + (l & 15);
  const int abyte = (arow * 64 + kslot * 16) ^ ((arow & 7) << 4);
  int bbyte[4];
  #pragma unroll
  for (int g = 0; g < 4; ++g) {
    int brow = g * 16 + (l & 15);
    bbyte[g] = (brow * 64 + kslot * 16) ^ ((brow & 7) << 4);
  }

  f32x4 acc[4];
  #pragma unroll
  for (int g = 0; g < 4; ++g) acc[g] = (f32x4){0.f, 0.f, 0.f, 0.f};

  uint4 av = *(const uint4*)gA;
  uint4 bv = *(const uint4*)gB;
  for (int kt = 0; kt < kiters; ++kt) {
    __syncthreads();
    *(uint4*)((char*)A_lds + wbyte) = av;
    *(uint4*)((char*)B_lds + wbyte) = bv;
    __syncthreads();
    uint4 an = av, bn = bv;
    if (kt + 1 < kiters) {
      an = *(const uint4*)(gA + (kt + 1) * 32);
      bn = *(const uint4*)(gB + (kt + 1) * 32);
    }
    short8 a = *(const short8*)((const char*)A_lds + abyte);
    #pragma unroll
    for (int g = 0; g < 4; ++g) {
      short8 bb = *(const short8*)((const char*)B_lds + bbyte[g]);
      acc[g] = __builtin_amdgcn_mfma_f32_16x16x32_bf16(a, bb, acc[g], 0, 0, 0);
    }
    av = an; bv = bn;
  }

  #pragma unroll
  for (int g = 0; g < 4; ++g) {
    int t = t0 + g * 16 + (l & 15);
    if (t >= Nvalid) continue;
    #pragma unroll
    for (int r = 0; r < 4; ++r) {
      int co = co0 + w * 16 + kslot * 4 + r;
      if (MODE == 1) {
        if (co < outCols) {
          float v = 0.f;
          if (co < M) {
            v = acc[g][r] + bias[co];
            if (RELU) v = v > 0.f ? v : 0.f;
          }
          ((short*)outv)[(size_t)b * outBatchStride + (size_t)t * outLD + co] = f2bf(v);
        }
      } else {
        if (co < M) {
          float v = acc[g][r] + bias[co];
          if (RELU) v = v > 0.f ? v : 0.f;
          ((float*)outv)[(size_t)b * outBatchStride + (size_t)co * outLD + t] = v;
        }
      }
    }
  }
}

// ===========================================================================
// Stage kernels (overlay-aware packing, verbatim R25/R26)
// ===========================================================================

// stageA: cvt_weights [0,6976) | im2col_k [6976,7200)
__global__ __launch_bounds__(256) void stageA_kernel(
    const float* __restrict__ kw1, const float* __restrict__ kw2,
    const float* __restrict__ qw1, const float* __restrict__ qw2,
    const float* __restrict__ qw3, short* __restrict__ w1bf,
    short* __restrict__ w2bf, short* __restrict__ w1q,
    short* __restrict__ w2q, short* __restrict__ w3q,
    const float* __restrict__ keys, short* __restrict__ BmatT) {
  __shared__ float sq[64 * 66];
  int flat = blockIdx.x;
  if (flat < 6976) {
    cvt_weights_body(flat, kw1, kw2, qw1, qw2, qw3, w1bf, w2bf, w1q, w2q, w3q);
  } else {
    im2col_k_body(flat - 6976, keys, BmatT, sq);
  }
}

// ---------------------------------------------------------------------------
// Key conv1 via MFMA v6 (verbatim R26): 128x128 tile, BK=64, gload_lds(16B).
// ---------------------------------------------------------------------------
__global__ __launch_bounds__(256) void kconv1_mfma_kernel(
    const short* __restrict__ w1bf, const short* __restrict__ BmatT,
    const float* __restrict__ b1, short* __restrict__ k1t) {
  __shared__ short A_lds[8192];
  __shared__ short B_lds[8192];
  const int flat = blockIdx.x;
  const int cox = flat >> 7;
  const int rem = flat & 127;
  const int b   = rem >> 2;
  const int ty  = rem & 3;
  const int co0 = cox * 128;
  const int t0  = ty * 128;
  const int tid = threadIdx.x;
  const int l = tid & 63, w = tid >> 6;

  const short* gsrc[8];
  short* ldst[8];
  #pragma unroll
  for (int j = 0; j < 8; ++j) {
    int c = w * 8 + j;
    int Y = (c & 15) * 1024 + l * 16;
    int X = Y ^ (((Y >> 7) & 7) << 4);     // self-inverse swizzle
    int row = X >> 7, slot = (X >> 4) & 7;
    if (c < 16) {
      gsrc[j] = w1bf + (size_t)(co0 + row) * KDIM + slot * 8;
      ldst[j] = &A_lds[(c & 15) * 512];
    } else {
      int gr = t0 + row;
      if (gr > TPAD - 1) gr = TPAD - 1;
      gsrc[j] = BmatT + ((size_t)b * TPAD + gr) * KDIM + slot * 8;
      ldst[j] = &B_lds[(c & 15) * 512];
    }
  }

  const int kslot = l >> 4;
  const int li15 = l & 15;
  int abyte[2][2], bbyte[8][2];
  #pragma unroll
  for (int i = 0; i < 2; ++i) {
    int arow = w * 32 + i * 16 + li15;
    #pragma unroll
    for (int kk = 0; kk < 2; ++kk)
      abyte[i][kk] = (arow * 128 + kk * 64 + kslot * 16) ^ ((arow & 7) << 4);
  }
  #pragma unroll
  for (int g = 0; g < 8; ++g) {
    int brow = g * 16 + li15;
    #pragma unroll
    for (int kk = 0; kk < 2; ++kk)
      bbyte[g][kk] = (brow * 128 + kk * 64 + kslot * 16) ^ ((brow & 7) << 4);
  }

  f32x4 acc[2][8];
  #pragma unroll
  for (int i = 0; i < 2; ++i)
    #pragma unroll
    for (int g = 0; g < 8; ++g) acc[i][g] = (f32x4){0.f, 0.f, 0.f, 0.f};

  for (int kt = 0; kt < KDIM / 64; ++kt) {
    __syncthreads();
    #pragma unroll
    for (int j = 0; j < 8; ++j) gload_lds16(gsrc[j] + kt * 64, ldst[j]);
    __syncthreads();
    #pragma unroll
    for (int kk = 0; kk < 2; ++kk) {
      short8 a0 = *(const short8*)((const char*)A_lds + abyte[0][kk]);
      short8 a1 = *(const short8*)((const char*)A_lds + abyte[1][kk]);
      #pragma unroll
      for (int g = 0; g < 8; ++g) {
        short8 bb = *(const short8*)((const char*)B_lds + bbyte[g][kk]);
        acc[0][g] = __builtin_amdgcn_mfma_f32_16x16x32_bf16(a0, bb, acc[0][g], 0, 0, 0);
        acc[1][g] = __builtin_amdgcn_mfma_f32_16x16x32_bf16(a1, bb, acc[1][g], 0, 0, 0);
      }
    }
  }

  #pragma unroll
  for (int g = 0; g < 8; ++g) {
    int t = t0 + g * 16 + li15;
    if (t < TEN) {
      #pragma unroll
      for (int i = 0; i < 2; ++i) {
        #pragma unroll
        for (int r = 0; r < 4; ++r) {
          int co = co0 + w * 32 + i * 16 + kslot * 4 + r;
          float v = acc[i][g][r] + b1[co];
          k1t[((size_t)b * TPAD + t) * C1 + co] = f2bf(v > 0.f ? v : 0.f);
        }
      }
    }
  }
}

// stageC: im2col_q [0,1024) | kconv2-GEMM [1024,1472)  (verbatim R25/R26)
__global__ __launch_bounds__(256) void stageC_kernel(
    const float* __restrict__ queries, short* __restrict__ Bq,
    const short* __restrict__ w2bf, const short* __restrict__ k1t,
    const float* __restrict__ kb2, short* __restrict__ kB) {
  __shared__ __align__(16) char pool[21120];
  int flat = blockIdx.x;
  if (flat < 1024) {
    im2col_q_body(flat, queries, Bq, (float*)pool);
  } else {
    int j = flat - 1024;
    int bx = j & 1, rest = j >> 1;
    int by = rest % 7, bz = rest / 7;
    qgemm_body<1, false>(bx, by, bz, w2bf, k1t, kb2, kB, CA, C1, 32, TEN, 96,
                         (size_t)TPAD * C1, (size_t)TPAD * 96, 96,
                         (short*)pool, (short*)(pool + 4096));
  }
}

// ---------------------------------------------------------------------------
// Standalone qgemm (verbatim R25/R26)
// ---------------------------------------------------------------------------
template <int MODE, bool RELU>
__global__ __launch_bounds__(256) void qgemm_kernel(
    const short* __restrict__ A, const short* __restrict__ B,
    const float* __restrict__ bias, void* __restrict__ outv,
    int M, int Kpad, int kiters, int Nvalid, int outCols,
    size_t bBatchStride, size_t outBatchStride, int outLD) {
  __shared__ short A_lds[2048];
  __shared__ short B_lds[2048];
  qgemm_body<MODE, RELU>(blockIdx.x, blockIdx.y, blockIdx.z, A, B, bias, outv,
                         M, Kpad, kiters, Nvalid, outCols, bBatchStride,
                         outBatchStride, outLD, A_lds, B_lds);
}

// ---------------------------------------------------------------------------
// FUSED attention v2: QK^T MFMA + IN-KERNEL norms + logp + softmax.
// q2 computed from staged A_lds (same summation scheme as old norms_kernel
// -> bit-identical); k2 computed per B-tile from staged B_lds.
// ---------------------------------------------------------------------------
__global__ __launch_bounds__(256) void attn_fused_kernel(
    const short* __restrict__ qA, const short* __restrict__ kB,
    const int* __restrict__ mask, float* __restrict__ out_attn,
    float* __restrict__ out_logp) {
  __shared__ short A_lds[3][2048];
  __shared__ short B_lds[3][2560];
  __shared__ float k2LDS[400];
  __shared__ float q2row[64];
  __shared__ int mLDS[400];
  const int t0 = blockIdx.x * 64;
  const int b  = blockIdx.y;
  const int tid = threadIdx.x;
  const int l = tid & 63, w = tid >> 6;

  {
    const int arow_s = tid >> 2, aslot = tid & 3;
    const short* gA = qA + ((size_t)b * TQP + t0 + arow_s) * 96 + aslot * 8;
    #pragma unroll
    for (int p = 0; p < 3; ++p) {
      uint4 v = *(const uint4*)(gA + p * 32);
      *(uint4*)((char*)&A_lds[p][0] +
                ((arow_s * 64 + aslot * 16) ^ ((arow_s & 7) << 4))) = v;
    }
  }
  for (int idx = tid; idx < 400; idx += 256) {
    mLDS[idx] = mask[(size_t)b * TEN + idx];
  }

  const int kslot = l >> 4;
  const int arow = w * 16 + (l & 15);
  const int abyte = (arow * 64 + kslot * 16) ^ ((arow & 7) << 4);

  f32x4 acc[25];
  #pragma unroll
  for (int i = 0; i < 25; ++i) acc[i] = (f32x4){0.f, 0.f, 0.f, 0.f};

  __syncthreads();

  // q2row from staged A (quarters-of-24 + shfl(1,2) — matches old norms_kernel)
  {
    int row = tid >> 2, g = tid & 3;
    float s = 0.f;
    #pragma unroll
    for (int q3i = 0; q3i < 3; ++q3i) {
      int q = 3 * g + q3i;
      int p = q >> 2, slot = q & 3;
      int byteo = (row * 64 + slot * 16) ^ ((row & 7) << 4);
      short8 v = *(const short8*)((const char*)&A_lds[p][0] + byteo);
      #pragma unroll
      for (int u = 0; u < 8; ++u) { float f = bf2f(v[u]); s += f * f; }
    }
    s += __shfl_xor(s, 1, 64);
    s += __shfl_xor(s, 2, 64);
    if (g == 0) q2row[row] = s;
  }

  #pragma unroll
  for (int st = 0; st < 5; ++st) {
    for (int idx = tid; idx < 960; idx += 256) {
      int row = idx / 12, c = idx - row * 12;
      int panel = c >> 2, ps = c & 3;
      uint4 v = *(const uint4*)(kB + ((size_t)b * TPAD + st * 80 + row) * 96 + c * 8);
      *(uint4*)((char*)&B_lds[panel][0] +
                ((row * 64 + ps * 16) ^ ((row & 7) << 4))) = v;
    }
    __syncthreads();
    // k2 for this tile's 80 rows (2 lanes/row, 48 cols each, shfl(1))
    if (tid < 160) {
      int row = tid >> 1, h = tid & 1;
      float s = 0.f;
      #pragma unroll
      for (int qi = 0; qi < 6; ++qi) {
        int q = 6 * h + qi;
        int p = q >> 2, slot = q & 3;
        int byteo = (row * 64 + slot * 16) ^ ((row & 7) << 4);
        short8 v = *(const short8*)((const char*)&B_lds[p][0] + byteo);
        #pragma unroll
        for (int u = 0; u < 8; ++u) { float f = bf2f(v[u]); s += f * f; }
      }
      s += __shfl_xor(s, 1, 64);
      if (h == 0) k2LDS[st * 80 + row] = s;
    }
    #pragma unroll
    for (int kt = 0; kt < 3; ++kt) {
      short8 a = *(const short8*)((const char*)&A_lds[kt][0] + abyte);
      #pragma unroll
      for (int f = 0; f < 5; ++f) {
        int brow = f * 16 + (l & 15);
        short8 bb = *(const short8*)((const char*)&B_lds[kt][0] +
                                     ((brow * 64 + kslot * 16) ^ ((brow & 7) << 4)));
        acc[st * 5 + f] =
            __builtin_amdgcn_mfma_f32_16x16x32_bf16(a, bb, acc[st * 5 + f], 0, 0, 0);
      }
    }
    __syncthreads();
  }

  int trow[4]; float q2v[4];
  #pragma unroll
  for (int r = 0; r < 4; ++r) {
    trow[r] = t0 + w * 16 + kslot * 4 + r;
    q2v[r] = q2row[w * 16 + kslot * 4 + r];
  }
  #pragma unroll
  for (int sf = 0; sf < 25; ++sf) {
    int s = sf * 16 + (l & 15);
    float k2v = k2LDS[s];
    bool mk = mLDS[s] != 0;
    #pragma unroll
    for (int r = 0; r < 4; ++r) {
      float lp = mk ? (-TEMP) * (q2v[r] + k2v - 2.f * acc[sf][r]) : -INFINITY;
      acc[sf][r] = lp;
    }
  }
  #pragma unroll
  for (int r = 0; r < 4; ++r) {
    if (trow[r] < TDE) {
      float* dst = out_logp + ((size_t)(b * TDE + trow[r])) * TEN + (l & 15);
      #pragma unroll
      for (int sf = 0; sf < 25; ++sf) dst[sf * 16] = acc[sf][r];
    }
  }
  float m[4];
  #pragma unroll
  for (int r = 0; r < 4; ++r) m[r] = -INFINITY;
  #pragma unroll
  for (int sf = 0; sf < 25; ++sf)
    #pragma unroll
    for (int r = 0; r < 4; ++r) m[r] = fmaxf(m[r], acc[sf][r]);
  #pragma unroll
  for (int o = 1; o < 16; o <<= 1)
    #pragma unroll
    for (int r = 0; r < 4; ++r) m[r] = fmaxf(m[r], __shfl_xor(m[r], o, 64));
  float sum[4] = {0.f, 0.f, 0.f, 0.f};
  #pragma unroll
  for (int sf = 0; sf < 25; ++sf)
    #pragma unroll
    for (int r = 0; r < 4; ++r) {
      float v = acc[sf][r];
      float e = (v != -INFINITY) ? __expf(v - m[r]) : 0.f;
      acc[sf][r] = e;
      sum[r] += e;
    }
  #pragma unroll
  for (int o = 1; o < 16; o <<= 1)
    #pragma unroll
    for (int r = 0; r < 4; ++r) sum[r] += __shfl_xor(sum[r], o, 64);
  float inv[4];
  #pragma unroll
  for (int r = 0; r < 4; ++r) inv[r] = 1.0f / sum[r];
  #pragma unroll
  for (int r = 0; r < 4; ++r) {
    if (trow[r] < TDE) {
      float* dst = out_attn + ((size_t)(b * TDE + trow[r])) * TEN + (l & 15);
      #pragma unroll
      for (int sf = 0; sf < 25; ++sf) dst[sf * 16] = acc[sf][r] * inv[r];
    }
  }
}

extern "C" void kernel_launch(void* const* d_in, const int* in_sizes, int n_in,
                              void* d_out, int out_size, void* d_ws, size_t ws_size,
                              hipStream_t stream) {
  const float* queries = (const float*)d_in[0];
  const float* keys    = (const float*)d_in[1];
  const int*   mask    = (const int*)d_in[2];
  const float* kw1 = (const float*)d_in[3];
  const float* kb1 = (const float*)d_in[4];
  const float* kw2 = (const float*)d_in[5];
  const float* kb2 = (const float*)d_in[6];
  const float* qw1 = (const float*)d_in[7];
  const float* qb1 = (const float*)d_in[8];
  const float* qw2 = (const float*)d_in[9];
  const float* qb2 = (const float*)d_in[10];
  const float* qw3 = (const float*)d_in[11];
  const float* qb3 = (const float*)d_in[12];
  float* out = (float*)d_out;

  char* ws = (char*)d_ws;
  short* BmatT = (short*)ws;
  short* w1bf  = (short*)(ws + 44040192);
  short* k1t   = (short*)(ws + 47185920);
  short* w2bf  = (short*)(ws + 76546048);
  short* w1q   = (short*)(ws + 76808192);
  short* w2q   = (short*)(ws + 76906496);
  short* w3q   = (short*)(ws + 76947456);
  short* Bq    = (short*)ws;
  short* q1bf  = (short*)(ws + 33554432);
  short* q2bf  = (short*)(ws + 54525952);
  short* qA    = (short*)(ws + 20480000);
  short* kB    = (short*)(ws + 81920000);

  const long long HALF = 25600000LL;
  float* out_attn = out;
  float* out_logp = out + HALF;

  // stageA: weights cvt + im2col_k (disjoint outputs)
  stageA_kernel<<<dim3(7200), dim3(256), 0, stream>>>(
      kw1, kw2, qw1, qw2, qw3, w1bf, w2bf, w1q, w2q, w3q, keys, BmatT);

  // kconv1 (consumes BmatT)
  kconv1_mfma_kernel<<<dim3(1024), dim3(256), 0, stream>>>(w1bf, BmatT, kb1, k1t);

  // stageC: im2col_q + kconv2-GEMM
  stageC_kernel<<<dim3(1472), dim3(256), 0, stream>>>(
      queries, Bq, w2bf, k1t, kb2, kB);

  // query GEMM chain
  qgemm_kernel<1, true><<<dim3(3, TQP / 64, NB), dim3(256), 0, stream>>>(
      w1q, Bq, qb1, q1bf, CQ2, 256, 8, TQP, 160,
      (size_t)TQP * 256, (size_t)TQP * 160, 160);
  qgemm_kernel<1, true><<<dim3(2, TQP / 64, NB), dim3(256), 0, stream>>>(
      w2q, q1bf, qb2, q2bf, CA, 160, 5, TQP, 96,
      (size_t)TQP * 160, (size_t)TQP * 96, 96);
  qgemm_kernel<1, false><<<dim3(2, TQP / 64, NB), dim3(256), 0, stream>>>(
      w3q, q2bf, qb3, qA, CA, 96, 3, TQP, 96,
      (size_t)TQP * 96, (size_t)TQP * 96, 96);

  // fused attention (norms computed in-kernel)
  attn_fused_kernel<<<dim3(TQP / 64, NB), dim3(256), 0, stream>>>(
      qA, kB, mask, out_attn, out_logp);
}